// Round 8
// baseline (511.231 us; speedup 1.0000x reference)
//
#include <hip/hip_runtime.h>

#define N_NODES 50000
#define N_EDGES 800000
#define NBLKA 200                 // Phase-A blocks; 800000/200 = 4000 edges each
#define EPB (N_EDGES / NBLKA)     // 4000
#define NBUCK 196                 // ceil(50000/256) buckets of 256 nodes
#define MSCAN (256 * NBLKA)       // 51200 hist entries to scan

// ---------------------------------------------------------------------------
// Phase A1: per-block 256-bin histogram of dst>>8, bin-major global layout
__global__ void histA_kernel(const int* __restrict__ dst, int* __restrict__ hist) {
    __shared__ int h[256];
    h[threadIdx.x] = 0;
    __syncthreads();
    int base = blockIdx.x * EPB;
    for (int i = base + threadIdx.x; i < base + EPB; i += 256)
        atomicAdd(&h[dst[i] >> 8], 1);
    __syncthreads();
    hist[threadIdx.x * NBLKA + blockIdx.x] = h[threadIdx.x];
}

// ---------------------------------------------------------------------------
// Hierarchical exclusive scan (generic): in -> out (block-local), bsum per block
__global__ void scan1_kernel(const int* __restrict__ in, int* __restrict__ out,
                             int* __restrict__ bsum, int n) {
    __shared__ int s[256];
    int i = blockIdx.x * 256 + threadIdx.x;
    int v = (i < n) ? in[i] : 0;
    s[threadIdx.x] = v;
    __syncthreads();
    for (int d = 1; d < 256; d <<= 1) {
        int t = (threadIdx.x >= d) ? s[threadIdx.x - d] : 0;
        __syncthreads();
        s[threadIdx.x] += t;
        __syncthreads();
    }
    if (i < n) out[i] = s[threadIdx.x] - v;
    if (threadIdx.x == 255) bsum[blockIdx.x] = s[255];
}

__global__ void scan2_kernel(int* __restrict__ bsum, int* __restrict__ boff, int nb) {
    __shared__ int s[256];
    int t = threadIdx.x;
    int v = (t < nb) ? bsum[t] : 0;
    s[t] = v;
    __syncthreads();
    for (int d = 1; d < 256; d <<= 1) {
        int x = (t >= d) ? s[t - d] : 0;
        __syncthreads();
        s[t] += x;
        __syncthreads();
    }
    if (t < nb) boff[t] = s[t] - v;
    if (t == nb - 1) boff[nb] = s[t];
}

__global__ void scan3_kernel(int* __restrict__ out, const int* __restrict__ boff,
                             int n, int nb) {
    int i = blockIdx.x * 256 + threadIdx.x;
    if (i < n) out[i] += boff[blockIdx.x];
    if (i == n - 1) out[n] = boff[nb];
}

// ---------------------------------------------------------------------------
// Phase A2: scatter (src,dst) pairs to bucket-major ebuf using per-(block,bin)
// offsets from the scanned histogram. Runs are contiguous -> ~full-line writes.
__global__ void scatterA_kernel(const int* __restrict__ src, const int* __restrict__ dst,
                                const int* __restrict__ scanned, int2* __restrict__ ebuf) {
    __shared__ int off[256];
    off[threadIdx.x] = scanned[threadIdx.x * NBLKA + blockIdx.x];
    __syncthreads();
    int base = blockIdx.x * EPB;
    for (int i = base + threadIdx.x; i < base + EPB; i += 256) {
        int s = src[i];
        int d = dst[i];
        int p = atomicAdd(&off[d >> 8], 1);
        ebuf[p] = make_int2(s, d);
    }
}

// ---------------------------------------------------------------------------
// Phase B: one block per 256-node bucket. Counts per-node degree in LDS,
// LDS-scan -> rowstart + dinv, then LDS-cursor scatter of esrc (no global
// atomics; each bucket's esrc region is written by exactly one block).
__global__ void bucket_kernel(const int2* __restrict__ ebuf, const int* __restrict__ scanned,
                              int* __restrict__ rowstart, float* __restrict__ dinv,
                              int* __restrict__ esrc) {
    __shared__ int cnt[256];
    __shared__ int cur[256];
    __shared__ int s[256];
    int k = blockIdx.x;
    int tid = threadIdx.x;
    int base = scanned[k * NBLKA];
    int end  = scanned[(k + 1) * NBLKA];
    cnt[tid] = 0;
    __syncthreads();
    for (int i = base + tid; i < end; i += 256)
        atomicAdd(&cnt[ebuf[i].y & 255], 1);
    __syncthreads();
    int v = cnt[tid];
    s[tid] = v;
    __syncthreads();
    for (int d = 1; d < 256; d <<= 1) {
        int t = (tid >= d) ? s[tid - d] : 0;
        __syncthreads();
        s[tid] += t;
        __syncthreads();
    }
    int excl = s[tid] - v;
    int node = (k << 8) + tid;
    cur[tid] = base + excl;
    if (node < N_NODES) {
        rowstart[node] = base + excl;
        dinv[node] = rsqrtf((float)v + 1.0f);
    }
    if (k == 0 && tid == 0) rowstart[N_NODES] = N_EDGES;
    __syncthreads();
    for (int i = base + tid; i < end; i += 256) {
        int2 e = ebuf[i];
        int p = atomicAdd(&cur[e.y & 255], 1);
        esrc[p] = e.x;
    }
}

// ---------------------------------------------------------------------------
// W12 = W1 @ W2 (96x96 @ 96x64), bw = b1 @ W2
__global__ void wfuse_kernel(const float* __restrict__ W1, const float* __restrict__ W2,
                             const float* __restrict__ b1, float* __restrict__ W12,
                             float* __restrict__ bw) {
    int idx = blockIdx.x * blockDim.x + threadIdx.x;
    if (idx < 96 * 64) {
        int k = idx >> 6, nn = idx & 63;
        float s = 0.0f;
#pragma unroll
        for (int j = 0; j < 96; ++j) s = fmaf(W1[k * 96 + j], W2[j * 64 + nn], s);
        W12[idx] = s;
    } else if (idx < 96 * 64 + 64) {
        int nn = idx - 96 * 64;
        float s = 0.0f;
#pragma unroll
        for (int j = 0; j < 96; ++j) s = fmaf(b1[j], W2[j * 64 + nn], s);
        bw[nn] = s;
    }
}

// ---------------------------------------------------------------------------
// y[M,64] = A[M,96] @ W[96,64]. Register-tiled, LDS-only inner loop.
// 64x64 tile, 16x16 threads, 4x4 outputs/thread. NO local arrays anywhere
// (rule #20: indexed locals spill to scratch -> 623MB fetch in R5).
// Macro params renamed so they can't capture the .x/.y/.z/.w member tokens.
#define FMA4(ACC, SCL, WV)                                                     \
    ACC.x = fmaf(SCL, WV.x, ACC.x);                                            \
    ACC.y = fmaf(SCL, WV.y, ACC.y);                                            \
    ACC.z = fmaf(SCL, WV.z, ACC.z);                                            \
    ACC.w = fmaf(SCL, WV.w, ACC.w);

__global__ void gemm_kernel(const float* __restrict__ A, const float* __restrict__ W,
                            float* __restrict__ out, int M) {
    __shared__ float sW[96 * 64];     // [k][col]
    __shared__ float sA[64 * 100];    // [row][k], padded stride 100
    int tid = threadIdx.x;

    {   // stage W (coalesced float4)
        const float4* W4 = (const float4*)W;
        float4* sW4 = (float4*)sW;
        for (int i = tid; i < 96 * 16; i += 256) sW4[i] = W4[i];
    }
    long row0 = (long)blockIdx.x * 64;
    {   // stage A rows [row0, row0+64) (coalesced float4; clamp for tail block)
        const float4* A4 = (const float4*)A;
        long base4 = row0 * 24;                       // row0*96/4
        long lim = (long)M * 24 - 1;
        for (int f = tid; f < 64 * 24; f += 256) {
            long g = base4 + f;
            if (g > lim) g = lim;
            float4 v = A4[g];
            int r = f / 24, kc = f - r * 24;
            *(float4*)(sA + r * 100 + kc * 4) = v;
        }
    }
    __syncthreads();

    int tx = tid & 15;        // cols tx*4 .. tx*4+3
    int ty = tid >> 4;        // rows ty*4 .. ty*4+3
    float4 acc0 = {0, 0, 0, 0};
    float4 acc1 = {0, 0, 0, 0};
    float4 acc2 = {0, 0, 0, 0};
    float4 acc3 = {0, 0, 0, 0};
    const float* pa = sA + ty * 4 * 100;
    const float* pw = sW + tx * 4;

#pragma unroll
    for (int k = 0; k < 96; k += 4) {
        float4 a0 = *(const float4*)(pa + 0 * 100 + k);
        float4 a1 = *(const float4*)(pa + 1 * 100 + k);
        float4 a2 = *(const float4*)(pa + 2 * 100 + k);
        float4 a3 = *(const float4*)(pa + 3 * 100 + k);
        float4 w0 = *(const float4*)(pw + (k + 0) * 64);
        float4 w1 = *(const float4*)(pw + (k + 1) * 64);
        float4 w2 = *(const float4*)(pw + (k + 2) * 64);
        float4 w3 = *(const float4*)(pw + (k + 3) * 64);
        FMA4(acc0, a0.x, w0) FMA4(acc0, a0.y, w1) FMA4(acc0, a0.z, w2) FMA4(acc0, a0.w, w3)
        FMA4(acc1, a1.x, w0) FMA4(acc1, a1.y, w1) FMA4(acc1, a1.z, w2) FMA4(acc1, a1.w, w3)
        FMA4(acc2, a2.x, w0) FMA4(acc2, a2.y, w1) FMA4(acc2, a2.z, w2) FMA4(acc2, a2.w, w3)
        FMA4(acc3, a3.x, w0) FMA4(acc3, a3.y, w1) FMA4(acc3, a3.z, w2) FMA4(acc3, a3.w, w3)
    }

    long r0 = row0 + ty * 4;
    if (r0 + 0 < M) *(float4*)(out + (r0 + 0) * 64 + tx * 4) = acc0;
    if (r0 + 1 < M) *(float4*)(out + (r0 + 1) * 64 + tx * 4) = acc1;
    if (r0 + 2 < M) *(float4*)(out + (r0 + 2) * 64 + tx * 4) = acc2;
    if (r0 + 3 < M) *(float4*)(out + (r0 + 3) * 64 + tx * 4) = acc3;
}

// ---------------------------------------------------------------------------
// One 64-lane wave per node:
//   out[i,:] = di^2*y[i,:] + di * sum_e dinv[src_e]*y[src_e,:]   (+ FINAL bias)
template <bool FINAL>
__global__ void agg_kernel(const float* __restrict__ y, const int* __restrict__ rowstart,
                           const int* __restrict__ esrc, const float* __restrict__ dinv,
                           const float* __restrict__ bw, const float* __restrict__ b2,
                           float* __restrict__ out, int n) {
    int wid = (blockIdx.x * blockDim.x + threadIdx.x) >> 6;
    int lane = threadIdx.x & 63;
    if (wid >= n) return;
    int rs = rowstart[wid];
    int re = rowstart[wid + 1];
    float di = dinv[wid];
    float self = y[(long)wid * 64 + lane];
    float a0 = 0.0f, a1 = 0.0f, a2 = 0.0f, a3 = 0.0f;
    float sd = 0.0f;
    for (int base = rs; base < re; base += 64) {
        int idx = base + lane;
        bool ok = idx < re;
        int sj = ok ? esrc[idx] : 0;
        float dj = ok ? dinv[sj] : 0.0f;
        sd += dj;
        int nn = min(64, re - base);
        int j = 0;
        for (; j + 4 <= nn; j += 4) {
            int s0 = __shfl(sj, j + 0); float c0 = __shfl(dj, j + 0);
            int s1 = __shfl(sj, j + 1); float c1 = __shfl(dj, j + 1);
            int s2 = __shfl(sj, j + 2); float c2 = __shfl(dj, j + 2);
            int s3 = __shfl(sj, j + 3); float c3 = __shfl(dj, j + 3);
            float v0 = y[(long)s0 * 64 + lane];
            float v1 = y[(long)s1 * 64 + lane];
            float v2 = y[(long)s2 * 64 + lane];
            float v3 = y[(long)s3 * 64 + lane];
            a0 = fmaf(v0, c0, a0);
            a1 = fmaf(v1, c1, a1);
            a2 = fmaf(v2, c2, a2);
            a3 = fmaf(v3, c3, a3);
        }
        for (; j < nn; ++j) {
            int s0 = __shfl(sj, j); float c0 = __shfl(dj, j);
            a0 = fmaf(y[(long)s0 * 64 + lane], c0, a0);
        }
    }
    float acc = fmaf((a0 + a1) + (a2 + a3), di, self * di * di);
    if (FINAL) {
#pragma unroll
        for (int m = 1; m < 64; m <<= 1) sd += __shfl_xor(sd, m);
        float si = di * (di + sd);
        acc = fmaf(si, bw[lane], acc) + b2[lane];
    }
    out[(long)wid * 64 + lane] = acc;
}

// ---------------------------------------------------------------------------
extern "C" void kernel_launch(void* const* d_in, const int* in_sizes, int n_in,
                              void* d_out, int out_size, void* d_ws, size_t ws_size,
                              hipStream_t stream) {
    const float* x  = (const float*)d_in[0];
    const int*   ei = (const int*)d_in[1];
    const float* W1 = (const float*)d_in[2];
    const float* b1 = (const float*)d_in[3];
    const float* W2 = (const float*)d_in[4];
    const float* b2 = (const float*)d_in[5];
    float* out = (float*)d_out;

    const int* src = ei;
    const int* dst = ei + N_EDGES;

    // workspace layout (bytes); ebuf aliases z (disjoint lifetimes)
    char* ws = (char*)d_ws;
    float* dinv     = (float*)(ws + 0);                  // 204800
    int*   rowstart = (int*)  (ws + 204800);             // 200004 -> pad 204800
    int*   hist     = (int*)  (ws + 409600);             // 204800 (51200 ints)
    int*   scanned  = (int*)  (ws + 614400);             // 204804 -> pad 208896
    int*   bsum     = (int*)  (ws + 823296);             // 1024
    int*   boff     = (int*)  (ws + 824320);             // 1024
    float* W12      = (float*)(ws + 825344);             // 24576
    float* bw       = (float*)(ws + 849920);             // 512
    int*   esrc     = (int*)  (ws + 850432);             // 3200000
    float* y        = (float*)(ws + 4050432);            // 12800000
    int2*  ebuf     = (int2*) (ws + 16850432);           // 6400000 (aliases z)
    float* z        = (float*)(ws + 16850432);           // 12800000 (end 29.65MB)

    // Phase A: bucket edges by dst>>8 with full-line writes
    histA_kernel<<<NBLKA, 256, 0, stream>>>(dst, hist);
    scan1_kernel<<<MSCAN / 256, 256, 0, stream>>>(hist, scanned, bsum, MSCAN);
    scan2_kernel<<<1, 256, 0, stream>>>(bsum, boff, MSCAN / 256);
    scan3_kernel<<<MSCAN / 256, 256, 0, stream>>>(scanned, boff, MSCAN, MSCAN / 256);
    scatterA_kernel<<<NBLKA, 256, 0, stream>>>(src, dst, scanned, ebuf);

    // Phase B: per-bucket degree count + rowstart + dinv + LDS-cursor scatter
    bucket_kernel<<<NBUCK, 256, 0, stream>>>(ebuf, scanned, rowstart, dinv, esrc);

    // fused weights + single GEMM
    wfuse_kernel<<<(96 * 64 + 64 + 255) / 256, 256, 0, stream>>>(W1, W2, b1, W12, bw);
    gemm_kernel<<<(N_NODES + 63) / 64, 256, 0, stream>>>(x, W12, y, N_NODES);

    // two aggregation passes: z = N y ; out = N z + s*bw + b2
    int aggBlocks = (N_NODES + 3) / 4;  // one 64-lane wave per node, 4 waves/block
    agg_kernel<false><<<aggBlocks, 256, 0, stream>>>(y, rowstart, esrc, dinv, bw, b2, z, N_NODES);
    agg_kernel<true><<<aggBlocks, 256, 0, stream>>>(z, rowstart, esrc, dinv, bw, b2, out, N_NODES);
}

// Round 9
// 263.252 us; speedup vs baseline: 1.9420x; 1.9420x over previous
//
#include <hip/hip_runtime.h>

#define N_NODES 50000
#define N_EDGES 800000
#define NBLKA 200                 // Phase-A blocks; 800000/200 = 4000 edges each
#define EPB (N_EDGES / NBLKA)     // 4000
#define NBUCK 196                 // ceil(50000/256) buckets of 256 nodes
#define MSCAN (256 * NBLKA)       // 51200 hist entries to scan

// ---------------------------------------------------------------------------
// Phase A1: per-block 256-bin histogram of dst>>8, bin-major global layout
__global__ void histA_kernel(const int* __restrict__ dst, int* __restrict__ hist) {
    __shared__ int h[256];
    h[threadIdx.x] = 0;
    __syncthreads();
    int base = blockIdx.x * EPB;
    for (int i = base + threadIdx.x; i < base + EPB; i += 256)
        atomicAdd(&h[dst[i] >> 8], 1);
    __syncthreads();
    hist[threadIdx.x * NBLKA + blockIdx.x] = h[threadIdx.x];
}

// ---------------------------------------------------------------------------
// Hierarchical exclusive scan (generic): in -> out (block-local), bsum per block
__global__ void scan1_kernel(const int* __restrict__ in, int* __restrict__ out,
                             int* __restrict__ bsum, int n) {
    __shared__ int s[256];
    int i = blockIdx.x * 256 + threadIdx.x;
    int v = (i < n) ? in[i] : 0;
    s[threadIdx.x] = v;
    __syncthreads();
    for (int d = 1; d < 256; d <<= 1) {
        int t = (threadIdx.x >= d) ? s[threadIdx.x - d] : 0;
        __syncthreads();
        s[threadIdx.x] += t;
        __syncthreads();
    }
    if (i < n) out[i] = s[threadIdx.x] - v;
    if (threadIdx.x == 255) bsum[blockIdx.x] = s[255];
}

__global__ void scan2_kernel(int* __restrict__ bsum, int* __restrict__ boff, int nb) {
    __shared__ int s[256];
    int t = threadIdx.x;
    int v = (t < nb) ? bsum[t] : 0;
    s[t] = v;
    __syncthreads();
    for (int d = 1; d < 256; d <<= 1) {
        int x = (t >= d) ? s[t - d] : 0;
        __syncthreads();
        s[t] += x;
        __syncthreads();
    }
    if (t < nb) boff[t] = s[t] - v;
    if (t == nb - 1) boff[nb] = s[t];
}

__global__ void scan3_kernel(int* __restrict__ out, const int* __restrict__ boff,
                             int n, int nb) {
    int i = blockIdx.x * 256 + threadIdx.x;
    if (i < n) out[i] += boff[blockIdx.x];
    if (i == n - 1) out[n] = boff[nb];
}

// ---------------------------------------------------------------------------
// Phase A2: scatter (src,dst) pairs to bucket-major ebuf using per-(block,bin)
// offsets from the scanned histogram. Runs are contiguous -> ~full-line writes.
__global__ void scatterA_kernel(const int* __restrict__ src, const int* __restrict__ dst,
                                const int* __restrict__ scanned, int2* __restrict__ ebuf) {
    __shared__ int off[256];
    off[threadIdx.x] = scanned[threadIdx.x * NBLKA + blockIdx.x];
    __syncthreads();
    int base = blockIdx.x * EPB;
    for (int i = base + threadIdx.x; i < base + EPB; i += 256) {
        int s = src[i];
        int d = dst[i];
        int p = atomicAdd(&off[d >> 8], 1);
        ebuf[p] = make_int2(s, d);
    }
}

// ---------------------------------------------------------------------------
// Phase B: one block per 256-node bucket. Counts per-node degree in LDS,
// LDS-scan -> rowstart + dinv, then LDS-cursor scatter of esrc (no global
// atomics; each bucket's esrc region is written by exactly one block).
__global__ void bucket_kernel(const int2* __restrict__ ebuf, const int* __restrict__ scanned,
                              int* __restrict__ rowstart, float* __restrict__ dinv,
                              int* __restrict__ esrc) {
    __shared__ int cnt[256];
    __shared__ int cur[256];
    __shared__ int s[256];
    int k = blockIdx.x;
    int tid = threadIdx.x;
    int base = scanned[k * NBLKA];
    int end  = scanned[(k + 1) * NBLKA];
    cnt[tid] = 0;
    __syncthreads();
    for (int i = base + tid; i < end; i += 256)
        atomicAdd(&cnt[ebuf[i].y & 255], 1);
    __syncthreads();
    int v = cnt[tid];
    s[tid] = v;
    __syncthreads();
    for (int d = 1; d < 256; d <<= 1) {
        int t = (tid >= d) ? s[tid - d] : 0;
        __syncthreads();
        s[tid] += t;
        __syncthreads();
    }
    int excl = s[tid] - v;
    int node = (k << 8) + tid;
    cur[tid] = base + excl;
    if (node < N_NODES) {
        rowstart[node] = base + excl;
        dinv[node] = rsqrtf((float)v + 1.0f);
    }
    if (k == 0 && tid == 0) rowstart[N_NODES] = N_EDGES;
    __syncthreads();
    for (int i = base + tid; i < end; i += 256) {
        int2 e = ebuf[i];
        int p = atomicAdd(&cur[e.y & 255], 1);
        esrc[p] = e.x;
    }
}

// ---------------------------------------------------------------------------
// W12 = W1 @ W2 (96x96 @ 96x64), bw = b1 @ W2
__global__ void wfuse_kernel(const float* __restrict__ W1, const float* __restrict__ W2,
                             const float* __restrict__ b1, float* __restrict__ W12,
                             float* __restrict__ bw) {
    int idx = blockIdx.x * blockDim.x + threadIdx.x;
    if (idx < 96 * 64) {
        int k = idx >> 6, nn = idx & 63;
        float s = 0.0f;
#pragma unroll
        for (int j = 0; j < 96; ++j) s = fmaf(W1[k * 96 + j], W2[j * 64 + nn], s);
        W12[idx] = s;
    } else if (idx < 96 * 64 + 64) {
        int nn = idx - 96 * 64;
        float s = 0.0f;
#pragma unroll
        for (int j = 0; j < 96; ++j) s = fmaf(b1[j], W2[j * 64 + nn], s);
        bw[nn] = s;
    }
}

// ---------------------------------------------------------------------------
// y[M,64] = A[M,96] @ W[96,64]. Register-tiled, LDS-only inner loop.
// 64x64 tile, 16x16 threads, 4x4 outputs/thread.
// __launch_bounds__(256) is ESSENTIAL: without it hipcc budgets for a
// 1024-thread workgroup -> 64-VGPR cap -> accumulators spill to scratch
// (640MB FETCH, 410us in R8). With it the allocator can use ~128 VGPRs.
#define FMA4(ACC, SCL, WV)                                                     \
    ACC.x = fmaf(SCL, WV.x, ACC.x);                                            \
    ACC.y = fmaf(SCL, WV.y, ACC.y);                                            \
    ACC.z = fmaf(SCL, WV.z, ACC.z);                                            \
    ACC.w = fmaf(SCL, WV.w, ACC.w);

__global__ __launch_bounds__(256)
void gemm_kernel(const float* __restrict__ A, const float* __restrict__ W,
                 float* __restrict__ out, int M) {
    __shared__ float sW[96 * 64];     // [k][col]
    __shared__ float sA[64 * 100];    // [row][k], padded stride 100
    int tid = threadIdx.x;

    {   // stage W (coalesced float4)
        const float4* W4 = (const float4*)W;
        float4* sW4 = (float4*)sW;
        for (int i = tid; i < 96 * 16; i += 256) sW4[i] = W4[i];
    }
    long row0 = (long)blockIdx.x * 64;
    {   // stage A rows [row0, row0+64) (coalesced float4; clamp for tail block)
        const float4* A4 = (const float4*)A;
        long base4 = row0 * 24;                       // row0*96/4
        long lim = (long)M * 24 - 1;
        for (int f = tid; f < 64 * 24; f += 256) {
            long g = base4 + f;
            if (g > lim) g = lim;
            float4 v = A4[g];
            int r = f / 24, kc = f - r * 24;
            *(float4*)(sA + r * 100 + kc * 4) = v;
        }
    }
    __syncthreads();

    int tx = tid & 15;        // cols tx*4 .. tx*4+3
    int ty = tid >> 4;        // rows ty*4 .. ty*4+3
    float4 acc0 = {0, 0, 0, 0};
    float4 acc1 = {0, 0, 0, 0};
    float4 acc2 = {0, 0, 0, 0};
    float4 acc3 = {0, 0, 0, 0};
    const float* pa = sA + ty * 4 * 100;
    const float* pw = sW + tx * 4;

#pragma unroll
    for (int k = 0; k < 96; k += 4) {
        float4 a0 = *(const float4*)(pa + 0 * 100 + k);
        float4 a1 = *(const float4*)(pa + 1 * 100 + k);
        float4 a2 = *(const float4*)(pa + 2 * 100 + k);
        float4 a3 = *(const float4*)(pa + 3 * 100 + k);
        float4 w0 = *(const float4*)(pw + (k + 0) * 64);
        float4 w1 = *(const float4*)(pw + (k + 1) * 64);
        float4 w2 = *(const float4*)(pw + (k + 2) * 64);
        float4 w3 = *(const float4*)(pw + (k + 3) * 64);
        FMA4(acc0, a0.x, w0) FMA4(acc0, a0.y, w1) FMA4(acc0, a0.z, w2) FMA4(acc0, a0.w, w3)
        FMA4(acc1, a1.x, w0) FMA4(acc1, a1.y, w1) FMA4(acc1, a1.z, w2) FMA4(acc1, a1.w, w3)
        FMA4(acc2, a2.x, w0) FMA4(acc2, a2.y, w1) FMA4(acc2, a2.z, w2) FMA4(acc2, a2.w, w3)
        FMA4(acc3, a3.x, w0) FMA4(acc3, a3.y, w1) FMA4(acc3, a3.z, w2) FMA4(acc3, a3.w, w3)
    }

    long r0 = row0 + ty * 4;
    if (r0 + 0 < M) *(float4*)(out + (r0 + 0) * 64 + tx * 4) = acc0;
    if (r0 + 1 < M) *(float4*)(out + (r0 + 1) * 64 + tx * 4) = acc1;
    if (r0 + 2 < M) *(float4*)(out + (r0 + 2) * 64 + tx * 4) = acc2;
    if (r0 + 3 < M) *(float4*)(out + (r0 + 3) * 64 + tx * 4) = acc3;
}

// ---------------------------------------------------------------------------
// One 64-lane wave per node:
//   out[i,:] = di^2*y[i,:] + di * sum_e dinv[src_e]*y[src_e,:]   (+ FINAL bias)
template <bool FINAL>
__global__ void agg_kernel(const float* __restrict__ y, const int* __restrict__ rowstart,
                           const int* __restrict__ esrc, const float* __restrict__ dinv,
                           const float* __restrict__ bw, const float* __restrict__ b2,
                           float* __restrict__ out, int n) {
    int wid = (blockIdx.x * blockDim.x + threadIdx.x) >> 6;
    int lane = threadIdx.x & 63;
    if (wid >= n) return;
    int rs = rowstart[wid];
    int re = rowstart[wid + 1];
    float di = dinv[wid];
    float self = y[(long)wid * 64 + lane];
    float a0 = 0.0f, a1 = 0.0f, a2 = 0.0f, a3 = 0.0f;
    float sd = 0.0f;
    for (int base = rs; base < re; base += 64) {
        int idx = base + lane;
        bool ok = idx < re;
        int sj = ok ? esrc[idx] : 0;
        float dj = ok ? dinv[sj] : 0.0f;
        sd += dj;
        int nn = min(64, re - base);
        int j = 0;
        for (; j + 4 <= nn; j += 4) {
            int s0 = __shfl(sj, j + 0); float c0 = __shfl(dj, j + 0);
            int s1 = __shfl(sj, j + 1); float c1 = __shfl(dj, j + 1);
            int s2 = __shfl(sj, j + 2); float c2 = __shfl(dj, j + 2);
            int s3 = __shfl(sj, j + 3); float c3 = __shfl(dj, j + 3);
            float v0 = y[(long)s0 * 64 + lane];
            float v1 = y[(long)s1 * 64 + lane];
            float v2 = y[(long)s2 * 64 + lane];
            float v3 = y[(long)s3 * 64 + lane];
            a0 = fmaf(v0, c0, a0);
            a1 = fmaf(v1, c1, a1);
            a2 = fmaf(v2, c2, a2);
            a3 = fmaf(v3, c3, a3);
        }
        for (; j < nn; ++j) {
            int s0 = __shfl(sj, j); float c0 = __shfl(dj, j);
            a0 = fmaf(y[(long)s0 * 64 + lane], c0, a0);
        }
    }
    float acc = fmaf((a0 + a1) + (a2 + a3), di, self * di * di);
    if (FINAL) {
#pragma unroll
        for (int m = 1; m < 64; m <<= 1) sd += __shfl_xor(sd, m);
        float si = di * (di + sd);
        acc = fmaf(si, bw[lane], acc) + b2[lane];
    }
    out[(long)wid * 64 + lane] = acc;
}

// ---------------------------------------------------------------------------
extern "C" void kernel_launch(void* const* d_in, const int* in_sizes, int n_in,
                              void* d_out, int out_size, void* d_ws, size_t ws_size,
                              hipStream_t stream) {
    const float* x  = (const float*)d_in[0];
    const int*   ei = (const int*)d_in[1];
    const float* W1 = (const float*)d_in[2];
    const float* b1 = (const float*)d_in[3];
    const float* W2 = (const float*)d_in[4];
    const float* b2 = (const float*)d_in[5];
    float* out = (float*)d_out;

    const int* src = ei;
    const int* dst = ei + N_EDGES;

    // workspace layout (bytes); ebuf aliases z (disjoint lifetimes)
    char* ws = (char*)d_ws;
    float* dinv     = (float*)(ws + 0);                  // 204800
    int*   rowstart = (int*)  (ws + 204800);             // 200004 -> pad 204800
    int*   hist     = (int*)  (ws + 409600);             // 204800 (51200 ints)
    int*   scanned  = (int*)  (ws + 614400);             // 204804 -> pad 208896
    int*   bsum     = (int*)  (ws + 823296);             // 1024
    int*   boff     = (int*)  (ws + 824320);             // 1024
    float* W12      = (float*)(ws + 825344);             // 24576
    float* bw       = (float*)(ws + 849920);             // 512
    int*   esrc     = (int*)  (ws + 850432);             // 3200000
    float* y        = (float*)(ws + 4050432);            // 12800000
    int2*  ebuf     = (int2*) (ws + 16850432);           // 6400000 (aliases z)
    float* z        = (float*)(ws + 16850432);           // 12800000 (end 29.65MB)

    // Phase A: bucket edges by dst>>8 with full-line writes
    histA_kernel<<<NBLKA, 256, 0, stream>>>(dst, hist);
    scan1_kernel<<<MSCAN / 256, 256, 0, stream>>>(hist, scanned, bsum, MSCAN);
    scan2_kernel<<<1, 256, 0, stream>>>(bsum, boff, MSCAN / 256);
    scan3_kernel<<<MSCAN / 256, 256, 0, stream>>>(scanned, boff, MSCAN, MSCAN / 256);
    scatterA_kernel<<<NBLKA, 256, 0, stream>>>(src, dst, scanned, ebuf);

    // Phase B: per-bucket degree count + rowstart + dinv + LDS-cursor scatter
    bucket_kernel<<<NBUCK, 256, 0, stream>>>(ebuf, scanned, rowstart, dinv, esrc);

    // fused weights + single GEMM
    wfuse_kernel<<<(96 * 64 + 64 + 255) / 256, 256, 0, stream>>>(W1, W2, b1, W12, bw);
    gemm_kernel<<<(N_NODES + 63) / 64, 256, 0, stream>>>(x, W12, y, N_NODES);

    // two aggregation passes: z = N y ; out = N z + s*bw + b2
    int aggBlocks = (N_NODES + 3) / 4;  // one 64-lane wave per node, 4 waves/block
    agg_kernel<false><<<aggBlocks, 256, 0, stream>>>(y, rowstart, esrc, dinv, bw, b2, z, N_NODES);
    agg_kernel<true><<<aggBlocks, 256, 0, stream>>>(z, rowstart, esrc, dinv, bw, b2, out, N_NODES);
}

// Round 10
// 124.100 us; speedup vs baseline: 4.1195x; 2.1213x over previous
//
#include <hip/hip_runtime.h>

#define N_NODES 50000
#define N_EDGES 800000
#define NBLKA 200                 // Phase-A blocks; 800000/200 = 4000 edges each
#define EPB (N_EDGES / NBLKA)     // 4000
#define NBUCK 196                 // ceil(50000/256) buckets of 256 nodes
#define MSCAN (256 * NBLKA)       // 51200 hist entries to scan

// ---------------------------------------------------------------------------
// Phase A1: per-block 256-bin histogram of dst>>8, bin-major global layout
__global__ void histA_kernel(const int* __restrict__ dst, int* __restrict__ hist) {
    __shared__ int h[256];
    h[threadIdx.x] = 0;
    __syncthreads();
    int base = blockIdx.x * EPB;
    for (int i = base + threadIdx.x; i < base + EPB; i += 256)
        atomicAdd(&h[dst[i] >> 8], 1);
    __syncthreads();
    hist[threadIdx.x * NBLKA + blockIdx.x] = h[threadIdx.x];
}

// ---------------------------------------------------------------------------
// Hierarchical exclusive scan (generic): in -> out (block-local), bsum per block
__global__ void scan1_kernel(const int* __restrict__ in, int* __restrict__ out,
                             int* __restrict__ bsum, int n) {
    __shared__ int s[256];
    int i = blockIdx.x * 256 + threadIdx.x;
    int v = (i < n) ? in[i] : 0;
    s[threadIdx.x] = v;
    __syncthreads();
    for (int d = 1; d < 256; d <<= 1) {
        int t = (threadIdx.x >= d) ? s[threadIdx.x - d] : 0;
        __syncthreads();
        s[threadIdx.x] += t;
        __syncthreads();
    }
    if (i < n) out[i] = s[threadIdx.x] - v;
    if (threadIdx.x == 255) bsum[blockIdx.x] = s[255];
}

__global__ void scan2_kernel(int* __restrict__ bsum, int* __restrict__ boff, int nb) {
    __shared__ int s[256];
    int t = threadIdx.x;
    int v = (t < nb) ? bsum[t] : 0;
    s[t] = v;
    __syncthreads();
    for (int d = 1; d < 256; d <<= 1) {
        int x = (t >= d) ? s[t - d] : 0;
        __syncthreads();
        s[t] += x;
        __syncthreads();
    }
    if (t < nb) boff[t] = s[t] - v;
    if (t == nb - 1) boff[nb] = s[t];
}

__global__ void scan3_kernel(int* __restrict__ out, const int* __restrict__ boff,
                             int n, int nb) {
    int i = blockIdx.x * 256 + threadIdx.x;
    if (i < n) out[i] += boff[blockIdx.x];
    if (i == n - 1) out[n] = boff[nb];
}

// ---------------------------------------------------------------------------
// Phase A2: scatter (src,dst) pairs to bucket-major ebuf using per-(block,bin)
// offsets from the scanned histogram. Runs are contiguous -> ~full-line writes.
__global__ void scatterA_kernel(const int* __restrict__ src, const int* __restrict__ dst,
                                const int* __restrict__ scanned, int2* __restrict__ ebuf) {
    __shared__ int off[256];
    off[threadIdx.x] = scanned[threadIdx.x * NBLKA + blockIdx.x];
    __syncthreads();
    int base = blockIdx.x * EPB;
    for (int i = base + threadIdx.x; i < base + EPB; i += 256) {
        int s = src[i];
        int d = dst[i];
        int p = atomicAdd(&off[d >> 8], 1);
        ebuf[p] = make_int2(s, d);
    }
}

// ---------------------------------------------------------------------------
// Phase B: one block per 256-node bucket. Counts per-node degree in LDS,
// LDS-scan -> rowstart + dinv, then LDS-cursor scatter of esrc (no global
// atomics; each bucket's esrc region is written by exactly one block).
__global__ void bucket_kernel(const int2* __restrict__ ebuf, const int* __restrict__ scanned,
                              int* __restrict__ rowstart, float* __restrict__ dinv,
                              int* __restrict__ esrc) {
    __shared__ int cnt[256];
    __shared__ int cur[256];
    __shared__ int s[256];
    int k = blockIdx.x;
    int tid = threadIdx.x;
    int base = scanned[k * NBLKA];
    int end  = scanned[(k + 1) * NBLKA];
    cnt[tid] = 0;
    __syncthreads();
    for (int i = base + tid; i < end; i += 256)
        atomicAdd(&cnt[ebuf[i].y & 255], 1);
    __syncthreads();
    int v = cnt[tid];
    s[tid] = v;
    __syncthreads();
    for (int d = 1; d < 256; d <<= 1) {
        int t = (tid >= d) ? s[tid - d] : 0;
        __syncthreads();
        s[tid] += t;
        __syncthreads();
    }
    int excl = s[tid] - v;
    int node = (k << 8) + tid;
    cur[tid] = base + excl;
    if (node < N_NODES) {
        rowstart[node] = base + excl;
        dinv[node] = rsqrtf((float)v + 1.0f);
    }
    if (k == 0 && tid == 0) rowstart[N_NODES] = N_EDGES;
    __syncthreads();
    for (int i = base + tid; i < end; i += 256) {
        int2 e = ebuf[i];
        int p = atomicAdd(&cur[e.y & 255], 1);
        esrc[p] = e.x;
    }
}

// ---------------------------------------------------------------------------
// W12 = W1 @ W2 (96x96 @ 96x64), bw = b1 @ W2
__global__ void wfuse_kernel(const float* __restrict__ W1, const float* __restrict__ W2,
                             const float* __restrict__ b1, float* __restrict__ W12,
                             float* __restrict__ bw) {
    int idx = blockIdx.x * blockDim.x + threadIdx.x;
    if (idx < 96 * 64) {
        int k = idx >> 6, nn = idx & 63;
        float s = 0.0f;
#pragma unroll
        for (int j = 0; j < 96; ++j) s = fmaf(W1[k * 96 + j], W2[j * 64 + nn], s);
        W12[idx] = s;
    } else if (idx < 96 * 64 + 64) {
        int nn = idx - 96 * 64;
        float s = 0.0f;
#pragma unroll
        for (int j = 0; j < 96; ++j) s = fmaf(b1[j], W2[j * 64 + nn], s);
        bw[nn] = s;
    }
}

// ---------------------------------------------------------------------------
// y[M,64] = A[M,96] @ W[96,64]. Register-tiled, LDS-only inner loop.
// 64x64 tile, 16x16 threads, 4x4 outputs/thread.
// __launch_bounds__(256): without it the 1024-thread default caps VGPR at 64
//   -> spill (R8: 640MB fetch).
// #pragma unroll 1 on the K loop: full unroll hoisted 24x8 ds_read results
//   -> ~770 live floats -> spill even at 256 VGPR (R9: 169MB fetch+write).
//   One iteration's live set (~80 regs) fits comfortably.
#define FMA4(ACC, SCL, WV)                                                     \
    ACC.x = fmaf(SCL, WV.x, ACC.x);                                            \
    ACC.y = fmaf(SCL, WV.y, ACC.y);                                            \
    ACC.z = fmaf(SCL, WV.z, ACC.z);                                            \
    ACC.w = fmaf(SCL, WV.w, ACC.w);

__global__ __launch_bounds__(256)
void gemm_kernel(const float* __restrict__ A, const float* __restrict__ W,
                 float* __restrict__ out, int M) {
    __shared__ float sW[96 * 64];     // [k][col]
    __shared__ float sA[64 * 100];    // [row][k], padded stride 100
    int tid = threadIdx.x;

    {   // stage W (coalesced float4)
        const float4* W4 = (const float4*)W;
        float4* sW4 = (float4*)sW;
        for (int i = tid; i < 96 * 16; i += 256) sW4[i] = W4[i];
    }
    long row0 = (long)blockIdx.x * 64;
    {   // stage A rows [row0, row0+64) (coalesced float4; clamp for tail block)
        const float4* A4 = (const float4*)A;
        long base4 = row0 * 24;                       // row0*96/4
        long lim = (long)M * 24 - 1;
        for (int f = tid; f < 64 * 24; f += 256) {
            long g = base4 + f;
            if (g > lim) g = lim;
            float4 v = A4[g];
            int r = f / 24, kc = f - r * 24;
            *(float4*)(sA + r * 100 + kc * 4) = v;
        }
    }
    __syncthreads();

    int tx = tid & 15;        // cols tx*4 .. tx*4+3
    int ty = tid >> 4;        // rows ty*4 .. ty*4+3
    float4 acc0 = {0, 0, 0, 0};
    float4 acc1 = {0, 0, 0, 0};
    float4 acc2 = {0, 0, 0, 0};
    float4 acc3 = {0, 0, 0, 0};
    const float* pa = sA + ty * 4 * 100;
    const float* pw = sW + tx * 4;

#pragma unroll 1
    for (int k = 0; k < 96; k += 4) {
        float4 a0 = *(const float4*)(pa + 0 * 100 + k);
        float4 a1 = *(const float4*)(pa + 1 * 100 + k);
        float4 a2 = *(const float4*)(pa + 2 * 100 + k);
        float4 a3 = *(const float4*)(pa + 3 * 100 + k);
        float4 w0 = *(const float4*)(pw + (k + 0) * 64);
        float4 w1 = *(const float4*)(pw + (k + 1) * 64);
        float4 w2 = *(const float4*)(pw + (k + 2) * 64);
        float4 w3 = *(const float4*)(pw + (k + 3) * 64);
        FMA4(acc0, a0.x, w0) FMA4(acc0, a0.y, w1) FMA4(acc0, a0.z, w2) FMA4(acc0, a0.w, w3)
        FMA4(acc1, a1.x, w0) FMA4(acc1, a1.y, w1) FMA4(acc1, a1.z, w2) FMA4(acc1, a1.w, w3)
        FMA4(acc2, a2.x, w0) FMA4(acc2, a2.y, w1) FMA4(acc2, a2.z, w2) FMA4(acc2, a2.w, w3)
        FMA4(acc3, a3.x, w0) FMA4(acc3, a3.y, w1) FMA4(acc3, a3.z, w2) FMA4(acc3, a3.w, w3)
    }

    long r0 = row0 + ty * 4;
    if (r0 + 0 < M) *(float4*)(out + (r0 + 0) * 64 + tx * 4) = acc0;
    if (r0 + 1 < M) *(float4*)(out + (r0 + 1) * 64 + tx * 4) = acc1;
    if (r0 + 2 < M) *(float4*)(out + (r0 + 2) * 64 + tx * 4) = acc2;
    if (r0 + 3 < M) *(float4*)(out + (r0 + 3) * 64 + tx * 4) = acc3;
}

// ---------------------------------------------------------------------------
// One 64-lane wave per node:
//   out[i,:] = di^2*y[i,:] + di * sum_e dinv[src_e]*y[src_e,:]   (+ FINAL bias)
template <bool FINAL>
__global__ void agg_kernel(const float* __restrict__ y, const int* __restrict__ rowstart,
                           const int* __restrict__ esrc, const float* __restrict__ dinv,
                           const float* __restrict__ bw, const float* __restrict__ b2,
                           float* __restrict__ out, int n) {
    int wid = (blockIdx.x * blockDim.x + threadIdx.x) >> 6;
    int lane = threadIdx.x & 63;
    if (wid >= n) return;
    int rs = rowstart[wid];
    int re = rowstart[wid + 1];
    float di = dinv[wid];
    float self = y[(long)wid * 64 + lane];
    float a0 = 0.0f, a1 = 0.0f, a2 = 0.0f, a3 = 0.0f;
    float sd = 0.0f;
    for (int base = rs; base < re; base += 64) {
        int idx = base + lane;
        bool ok = idx < re;
        int sj = ok ? esrc[idx] : 0;
        float dj = ok ? dinv[sj] : 0.0f;
        sd += dj;
        int nn = min(64, re - base);
        int j = 0;
        for (; j + 4 <= nn; j += 4) {
            int s0 = __shfl(sj, j + 0); float c0 = __shfl(dj, j + 0);
            int s1 = __shfl(sj, j + 1); float c1 = __shfl(dj, j + 1);
            int s2 = __shfl(sj, j + 2); float c2 = __shfl(dj, j + 2);
            int s3 = __shfl(sj, j + 3); float c3 = __shfl(dj, j + 3);
            float v0 = y[(long)s0 * 64 + lane];
            float v1 = y[(long)s1 * 64 + lane];
            float v2 = y[(long)s2 * 64 + lane];
            float v3 = y[(long)s3 * 64 + lane];
            a0 = fmaf(v0, c0, a0);
            a1 = fmaf(v1, c1, a1);
            a2 = fmaf(v2, c2, a2);
            a3 = fmaf(v3, c3, a3);
        }
        for (; j < nn; ++j) {
            int s0 = __shfl(sj, j); float c0 = __shfl(dj, j);
            a0 = fmaf(y[(long)s0 * 64 + lane], c0, a0);
        }
    }
    float acc = fmaf((a0 + a1) + (a2 + a3), di, self * di * di);
    if (FINAL) {
#pragma unroll
        for (int m = 1; m < 64; m <<= 1) sd += __shfl_xor(sd, m);
        float si = di * (di + sd);
        acc = fmaf(si, bw[lane], acc) + b2[lane];
    }
    out[(long)wid * 64 + lane] = acc;
}

// ---------------------------------------------------------------------------
extern "C" void kernel_launch(void* const* d_in, const int* in_sizes, int n_in,
                              void* d_out, int out_size, void* d_ws, size_t ws_size,
                              hipStream_t stream) {
    const float* x  = (const float*)d_in[0];
    const int*   ei = (const int*)d_in[1];
    const float* W1 = (const float*)d_in[2];
    const float* b1 = (const float*)d_in[3];
    const float* W2 = (const float*)d_in[4];
    const float* b2 = (const float*)d_in[5];
    float* out = (float*)d_out;

    const int* src = ei;
    const int* dst = ei + N_EDGES;

    // workspace layout (bytes); ebuf aliases z (disjoint lifetimes)
    char* ws = (char*)d_ws;
    float* dinv     = (float*)(ws + 0);                  // 204800
    int*   rowstart = (int*)  (ws + 204800);             // 200004 -> pad 204800
    int*   hist     = (int*)  (ws + 409600);             // 204800 (51200 ints)
    int*   scanned  = (int*)  (ws + 614400);             // 204804 -> pad 208896
    int*   bsum     = (int*)  (ws + 823296);             // 1024
    int*   boff     = (int*)  (ws + 824320);             // 1024
    float* W12      = (float*)(ws + 825344);             // 24576
    float* bw       = (float*)(ws + 849920);             // 512
    int*   esrc     = (int*)  (ws + 850432);             // 3200000
    float* y        = (float*)(ws + 4050432);            // 12800000
    int2*  ebuf     = (int2*) (ws + 16850432);           // 6400000 (aliases z)
    float* z        = (float*)(ws + 16850432);           // 12800000 (end 29.65MB)

    // Phase A: bucket edges by dst>>8 with full-line writes
    histA_kernel<<<NBLKA, 256, 0, stream>>>(dst, hist);
    scan1_kernel<<<MSCAN / 256, 256, 0, stream>>>(hist, scanned, bsum, MSCAN);
    scan2_kernel<<<1, 256, 0, stream>>>(bsum, boff, MSCAN / 256);
    scan3_kernel<<<MSCAN / 256, 256, 0, stream>>>(scanned, boff, MSCAN, MSCAN / 256);
    scatterA_kernel<<<NBLKA, 256, 0, stream>>>(src, dst, scanned, ebuf);

    // Phase B: per-bucket degree count + rowstart + dinv + LDS-cursor scatter
    bucket_kernel<<<NBUCK, 256, 0, stream>>>(ebuf, scanned, rowstart, dinv, esrc);

    // fused weights + single GEMM
    wfuse_kernel<<<(96 * 64 + 64 + 255) / 256, 256, 0, stream>>>(W1, W2, b1, W12, bw);
    gemm_kernel<<<(N_NODES + 63) / 64, 256, 0, stream>>>(x, W12, y, N_NODES);

    // two aggregation passes: z = N y ; out = N z + s*bw + b2
    int aggBlocks = (N_NODES + 3) / 4;  // one 64-lane wave per node, 4 waves/block
    agg_kernel<false><<<aggBlocks, 256, 0, stream>>>(y, rowstart, esrc, dinv, bw, b2, z, N_NODES);
    agg_kernel<true><<<aggBlocks, 256, 0, stream>>>(z, rowstart, esrc, dinv, bw, b2, out, N_NODES);
}

// Round 11
// 118.754 us; speedup vs baseline: 4.3050x; 1.0450x over previous
//
#include <hip/hip_runtime.h>

#define N_NODES 50000
#define N_EDGES 800000
#define NBLKA 200                 // Phase-A blocks; 800000/200 = 4000 edges each
#define EPB (N_EDGES / NBLKA)     // 4000
#define NBUCK 196                 // ceil(50000/256) buckets of 256 nodes
#define MSCAN (256 * NBLKA)       // 51200 hist entries to scan

// ---------------------------------------------------------------------------
// Phase A1: per-block 256-bin histogram of dst>>8, bin-major global layout
__global__ void histA_kernel(const int* __restrict__ dst, int* __restrict__ hist) {
    __shared__ int h[256];
    h[threadIdx.x] = 0;
    __syncthreads();
    int base = blockIdx.x * EPB;
    for (int i = base + threadIdx.x; i < base + EPB; i += 256)
        atomicAdd(&h[dst[i] >> 8], 1);
    __syncthreads();
    hist[threadIdx.x * NBLKA + blockIdx.x] = h[threadIdx.x];
}

// ---------------------------------------------------------------------------
// Hierarchical exclusive scan (generic): in -> out (block-local), bsum per block
__global__ void scan1_kernel(const int* __restrict__ in, int* __restrict__ out,
                             int* __restrict__ bsum, int n) {
    __shared__ int s[256];
    int i = blockIdx.x * 256 + threadIdx.x;
    int v = (i < n) ? in[i] : 0;
    s[threadIdx.x] = v;
    __syncthreads();
    for (int d = 1; d < 256; d <<= 1) {
        int t = (threadIdx.x >= d) ? s[threadIdx.x - d] : 0;
        __syncthreads();
        s[threadIdx.x] += t;
        __syncthreads();
    }
    if (i < n) out[i] = s[threadIdx.x] - v;
    if (threadIdx.x == 255) bsum[blockIdx.x] = s[255];
}

// scan2 (block 0) + wfuse (blocks 1..25) merged: independent work, one launch.
__global__ void scan2_wfuse_kernel(int* __restrict__ bsum, int* __restrict__ boff, int nb,
                                   const float* __restrict__ W1, const float* __restrict__ W2,
                                   const float* __restrict__ b1, float* __restrict__ W12,
                                   float* __restrict__ bw) {
    if (blockIdx.x == 0) {
        __shared__ int s[256];
        int t = threadIdx.x;
        int v = (t < nb) ? bsum[t] : 0;
        s[t] = v;
        __syncthreads();
        for (int d = 1; d < 256; d <<= 1) {
            int x = (t >= d) ? s[t - d] : 0;
            __syncthreads();
            s[t] += x;
            __syncthreads();
        }
        if (t < nb) boff[t] = s[t] - v;
        if (t == nb - 1) boff[nb] = s[t];
    } else {
        int idx = (blockIdx.x - 1) * 256 + threadIdx.x;
        if (idx < 96 * 64) {
            int k = idx >> 6, nn = idx & 63;
            float s = 0.0f;
#pragma unroll
            for (int j = 0; j < 96; ++j) s = fmaf(W1[k * 96 + j], W2[j * 64 + nn], s);
            W12[idx] = s;
        } else if (idx < 96 * 64 + 64) {
            int nn = idx - 96 * 64;
            float s = 0.0f;
#pragma unroll
            for (int j = 0; j < 96; ++j) s = fmaf(b1[j], W2[j * 64 + nn], s);
            bw[nn] = s;
        }
    }
}

__global__ void scan3_kernel(int* __restrict__ out, const int* __restrict__ boff,
                             int n, int nb) {
    int i = blockIdx.x * 256 + threadIdx.x;
    if (i < n) out[i] += boff[blockIdx.x];
    if (i == n - 1) out[n] = boff[nb];
}

// ---------------------------------------------------------------------------
// Phase A2: scatter (src,dst) pairs to bucket-major ebuf using per-(block,bin)
// offsets from the scanned histogram. Runs are contiguous -> ~full-line writes.
__global__ void scatterA_kernel(const int* __restrict__ src, const int* __restrict__ dst,
                                const int* __restrict__ scanned, int2* __restrict__ ebuf) {
    __shared__ int off[256];
    off[threadIdx.x] = scanned[threadIdx.x * NBLKA + blockIdx.x];
    __syncthreads();
    int base = blockIdx.x * EPB;
    for (int i = base + threadIdx.x; i < base + EPB; i += 256) {
        int s = src[i];
        int d = dst[i];
        int p = atomicAdd(&off[d >> 8], 1);
        ebuf[p] = make_int2(s, d);
    }
}

// ---------------------------------------------------------------------------
// Phase B: one block per 256-node bucket. Counts per-node degree in LDS,
// LDS-scan -> rowstart + dinv, then LDS-cursor scatter of esrc (no global
// atomics; each bucket's esrc region is written by exactly one block).
__global__ void bucket_kernel(const int2* __restrict__ ebuf, const int* __restrict__ scanned,
                              int* __restrict__ rowstart, float* __restrict__ dinv,
                              int* __restrict__ esrc) {
    __shared__ int cnt[256];
    __shared__ int cur[256];
    __shared__ int s[256];
    int k = blockIdx.x;
    int tid = threadIdx.x;
    int base = scanned[k * NBLKA];
    int end  = scanned[(k + 1) * NBLKA];
    cnt[tid] = 0;
    __syncthreads();
    for (int i = base + tid; i < end; i += 256)
        atomicAdd(&cnt[ebuf[i].y & 255], 1);
    __syncthreads();
    int v = cnt[tid];
    s[tid] = v;
    __syncthreads();
    for (int d = 1; d < 256; d <<= 1) {
        int t = (tid >= d) ? s[tid - d] : 0;
        __syncthreads();
        s[tid] += t;
        __syncthreads();
    }
    int excl = s[tid] - v;
    int node = (k << 8) + tid;
    cur[tid] = base + excl;
    if (node < N_NODES) {
        rowstart[node] = base + excl;
        dinv[node] = rsqrtf((float)v + 1.0f);
    }
    if (k == 0 && tid == 0) rowstart[N_NODES] = N_EDGES;
    __syncthreads();
    for (int i = base + tid; i < end; i += 256) {
        int2 e = ebuf[i];
        int p = atomicAdd(&cur[e.y & 255], 1);
        esrc[p] = e.x;
    }
}

// ---------------------------------------------------------------------------
// y[M,64] = A[M,96] @ W[96,64]. Register-tiled, LDS-only inner loop.
// 64x64 tile, 16x16 threads, 4x4 outputs/thread.
// __launch_bounds__(256): without it the 1024-thread default caps VGPR at 64
//   -> spill (R8: 640MB fetch).
// #pragma unroll 1 on the K loop: full unroll hoisted 24x8 ds_read results
//   -> ~770 live floats -> spill even at 256 VGPR (R9: 169MB fetch+write).
#define FMA4(ACC, SCL, WV)                                                     \
    ACC.x = fmaf(SCL, WV.x, ACC.x);                                            \
    ACC.y = fmaf(SCL, WV.y, ACC.y);                                            \
    ACC.z = fmaf(SCL, WV.z, ACC.z);                                            \
    ACC.w = fmaf(SCL, WV.w, ACC.w);

__global__ __launch_bounds__(256)
void gemm_kernel(const float* __restrict__ A, const float* __restrict__ W,
                 float* __restrict__ out, int M) {
    __shared__ float sW[96 * 64];     // [k][col]
    __shared__ float sA[64 * 100];    // [row][k], padded stride 100
    int tid = threadIdx.x;

    {   // stage W (coalesced float4)
        const float4* W4 = (const float4*)W;
        float4* sW4 = (float4*)sW;
        for (int i = tid; i < 96 * 16; i += 256) sW4[i] = W4[i];
    }
    long row0 = (long)blockIdx.x * 64;
    {   // stage A rows [row0, row0+64) (coalesced float4; clamp for tail block)
        const float4* A4 = (const float4*)A;
        long base4 = row0 * 24;                       // row0*96/4
        long lim = (long)M * 24 - 1;
        for (int f = tid; f < 64 * 24; f += 256) {
            long g = base4 + f;
            if (g > lim) g = lim;
            float4 v = A4[g];
            int r = f / 24, kc = f - r * 24;
            *(float4*)(sA + r * 100 + kc * 4) = v;
        }
    }
    __syncthreads();

    int tx = tid & 15;        // cols tx*4 .. tx*4+3
    int ty = tid >> 4;        // rows ty*4 .. ty*4+3
    float4 acc0 = {0, 0, 0, 0};
    float4 acc1 = {0, 0, 0, 0};
    float4 acc2 = {0, 0, 0, 0};
    float4 acc3 = {0, 0, 0, 0};
    const float* pa = sA + ty * 4 * 100;
    const float* pw = sW + tx * 4;

#pragma unroll 1
    for (int k = 0; k < 96; k += 4) {
        float4 a0 = *(const float4*)(pa + 0 * 100 + k);
        float4 a1 = *(const float4*)(pa + 1 * 100 + k);
        float4 a2 = *(const float4*)(pa + 2 * 100 + k);
        float4 a3 = *(const float4*)(pa + 3 * 100 + k);
        float4 w0 = *(const float4*)(pw + (k + 0) * 64);
        float4 w1 = *(const float4*)(pw + (k + 1) * 64);
        float4 w2 = *(const float4*)(pw + (k + 2) * 64);
        float4 w3 = *(const float4*)(pw + (k + 3) * 64);
        FMA4(acc0, a0.x, w0) FMA4(acc0, a0.y, w1) FMA4(acc0, a0.z, w2) FMA4(acc0, a0.w, w3)
        FMA4(acc1, a1.x, w0) FMA4(acc1, a1.y, w1) FMA4(acc1, a1.z, w2) FMA4(acc1, a1.w, w3)
        FMA4(acc2, a2.x, w0) FMA4(acc2, a2.y, w1) FMA4(acc2, a2.z, w2) FMA4(acc2, a2.w, w3)
        FMA4(acc3, a3.x, w0) FMA4(acc3, a3.y, w1) FMA4(acc3, a3.z, w2) FMA4(acc3, a3.w, w3)
    }

    long r0 = row0 + ty * 4;
    if (r0 + 0 < M) *(float4*)(out + (r0 + 0) * 64 + tx * 4) = acc0;
    if (r0 + 1 < M) *(float4*)(out + (r0 + 1) * 64 + tx * 4) = acc1;
    if (r0 + 2 < M) *(float4*)(out + (r0 + 2) * 64 + tx * 4) = acc2;
    if (r0 + 3 < M) *(float4*)(out + (r0 + 3) * 64 + tx * 4) = acc3;
}

// ---------------------------------------------------------------------------
// One 64-lane wave per node:
//   out[i,:] = di^2*y[i,:] + di * sum_e dinv[src_e]*y[src_e,:]   (+ FINAL bias)
// 8-deep unroll, 8 independent accumulators -> 8 gathers in flight
// (R10: 4-deep was latency-bound at ~28us/pass vs ~10us BW floor).
#define AGG_STEP(AC, JO)                                                       \
    {                                                                          \
        int sS = __shfl(sj, j + JO);                                           \
        float cS = __shfl(dj, j + JO);                                         \
        AC = fmaf(y[(long)sS * 64 + lane], cS, AC);                            \
    }

template <bool FINAL>
__global__ __launch_bounds__(256)
void agg_kernel(const float* __restrict__ y, const int* __restrict__ rowstart,
                const int* __restrict__ esrc, const float* __restrict__ dinv,
                const float* __restrict__ bw, const float* __restrict__ b2,
                float* __restrict__ out, int n) {
    int wid = (blockIdx.x * blockDim.x + threadIdx.x) >> 6;
    int lane = threadIdx.x & 63;
    if (wid >= n) return;
    int rs = rowstart[wid];
    int re = rowstart[wid + 1];
    float di = dinv[wid];
    float self = y[(long)wid * 64 + lane];
    float a0 = 0.0f, a1 = 0.0f, a2 = 0.0f, a3 = 0.0f;
    float a4 = 0.0f, a5 = 0.0f, a6 = 0.0f, a7 = 0.0f;
    float sd = 0.0f;
    for (int base = rs; base < re; base += 64) {
        int idx = base + lane;
        bool ok = idx < re;
        int sj = ok ? esrc[idx] : 0;
        float dj = ok ? dinv[sj] : 0.0f;
        sd += dj;
        int nn = min(64, re - base);
        int j = 0;
        for (; j + 8 <= nn; j += 8) {
            AGG_STEP(a0, 0) AGG_STEP(a1, 1) AGG_STEP(a2, 2) AGG_STEP(a3, 3)
            AGG_STEP(a4, 4) AGG_STEP(a5, 5) AGG_STEP(a6, 6) AGG_STEP(a7, 7)
        }
        for (; j + 2 <= nn; j += 2) {
            AGG_STEP(a0, 0) AGG_STEP(a1, 1)
        }
        for (; j < nn; ++j) {
            AGG_STEP(a0, 0)
        }
    }
    float esum = ((a0 + a1) + (a2 + a3)) + ((a4 + a5) + (a6 + a7));
    float acc = fmaf(esum, di, self * di * di);
    if (FINAL) {
#pragma unroll
        for (int m = 1; m < 64; m <<= 1) sd += __shfl_xor(sd, m);
        float si = di * (di + sd);
        acc = fmaf(si, bw[lane], acc) + b2[lane];
    }
    out[(long)wid * 64 + lane] = acc;
}

// ---------------------------------------------------------------------------
extern "C" void kernel_launch(void* const* d_in, const int* in_sizes, int n_in,
                              void* d_out, int out_size, void* d_ws, size_t ws_size,
                              hipStream_t stream) {
    const float* x  = (const float*)d_in[0];
    const int*   ei = (const int*)d_in[1];
    const float* W1 = (const float*)d_in[2];
    const float* b1 = (const float*)d_in[3];
    const float* W2 = (const float*)d_in[4];
    const float* b2 = (const float*)d_in[5];
    float* out = (float*)d_out;

    const int* src = ei;
    const int* dst = ei + N_EDGES;

    // workspace layout (bytes); ebuf aliases z (disjoint lifetimes)
    char* ws = (char*)d_ws;
    float* dinv     = (float*)(ws + 0);                  // 204800
    int*   rowstart = (int*)  (ws + 204800);             // 200004 -> pad 204800
    int*   hist     = (int*)  (ws + 409600);             // 204800 (51200 ints)
    int*   scanned  = (int*)  (ws + 614400);             // 204804 -> pad 208896
    int*   bsum     = (int*)  (ws + 823296);             // 1024
    int*   boff     = (int*)  (ws + 824320);             // 1024
    float* W12      = (float*)(ws + 825344);             // 24576
    float* bw       = (float*)(ws + 849920);             // 512
    int*   esrc     = (int*)  (ws + 850432);             // 3200000
    float* y        = (float*)(ws + 4050432);            // 12800000
    int2*  ebuf     = (int2*) (ws + 16850432);           // 6400000 (aliases z)
    float* z        = (float*)(ws + 16850432);           // 12800000 (end 29.65MB)

    // Phase A: bucket edges by dst>>8 with full-line writes
    histA_kernel<<<NBLKA, 256, 0, stream>>>(dst, hist);
    scan1_kernel<<<MSCAN / 256, 256, 0, stream>>>(hist, scanned, bsum, MSCAN);
    scan2_wfuse_kernel<<<26, 256, 0, stream>>>(bsum, boff, MSCAN / 256,
                                               W1, W2, b1, W12, bw);
    scan3_kernel<<<MSCAN / 256, 256, 0, stream>>>(scanned, boff, MSCAN, MSCAN / 256);
    scatterA_kernel<<<NBLKA, 256, 0, stream>>>(src, dst, scanned, ebuf);

    // Phase B: per-bucket degree count + rowstart + dinv + LDS-cursor scatter
    bucket_kernel<<<NBUCK, 256, 0, stream>>>(ebuf, scanned, rowstart, dinv, esrc);

    // single fused GEMM (W12 produced alongside scan2)
    gemm_kernel<<<(N_NODES + 63) / 64, 256, 0, stream>>>(x, W12, y, N_NODES);

    // two aggregation passes: z = N y ; out = N z + s*bw + b2
    int aggBlocks = (N_NODES + 3) / 4;  // one 64-lane wave per node, 4 waves/block
    agg_kernel<false><<<aggBlocks, 256, 0, stream>>>(y, rowstart, esrc, dinv, bw, b2, z, N_NODES);
    agg_kernel<true><<<aggBlocks, 256, 0, stream>>>(z, rowstart, esrc, dinv, bw, b2, out, N_NODES);
}

// Round 12
// 113.186 us; speedup vs baseline: 4.5167x; 1.0492x over previous
//
#include <hip/hip_runtime.h>

#define N_NODES 50000
#define N_EDGES 800000
#define NBLKA 200                 // Phase-A blocks; 800000/200 = 4000 edges each
#define EPB (N_EDGES / NBLKA)     // 4000
#define NBUCK 196                 // ceil(50000/256) buckets of 256 nodes
#define MSCAN (256 * NBLKA)       // 51200 hist entries to scan

// ---------------------------------------------------------------------------
// Phase A1: per-block 256-bin histogram of dst>>8, bin-major global layout
__global__ void histA_kernel(const int* __restrict__ dst, int* __restrict__ hist) {
    __shared__ int h[256];
    h[threadIdx.x] = 0;
    __syncthreads();
    int base = blockIdx.x * EPB;
    for (int i = base + threadIdx.x; i < base + EPB; i += 256)
        atomicAdd(&h[dst[i] >> 8], 1);
    __syncthreads();
    hist[threadIdx.x * NBLKA + blockIdx.x] = h[threadIdx.x];
}

// ---------------------------------------------------------------------------
// scan1: block-local exclusive scan of hist -> scanned (local), bsum per block
__global__ void scan1_kernel(const int* __restrict__ in, int* __restrict__ out,
                             int* __restrict__ bsum, int n) {
    __shared__ int s[256];
    int i = blockIdx.x * 256 + threadIdx.x;
    int v = (i < n) ? in[i] : 0;
    s[threadIdx.x] = v;
    __syncthreads();
    for (int d = 1; d < 256; d <<= 1) {
        int t = (threadIdx.x >= d) ? s[threadIdx.x - d] : 0;
        __syncthreads();
        s[threadIdx.x] += t;
        __syncthreads();
    }
    if (i < n) out[i] = s[threadIdx.x] - v;
    if (threadIdx.x == 255) bsum[blockIdx.x] = s[255];
}

// scan2 (block 0) + wfuse (blocks 1..25) merged: independent work, one launch.
// Consumers fold boff in directly (scan3 eliminated).
__global__ void scan2_wfuse_kernel(int* __restrict__ bsum, int* __restrict__ boff, int nb,
                                   const float* __restrict__ W1, const float* __restrict__ W2,
                                   const float* __restrict__ b1, float* __restrict__ W12,
                                   float* __restrict__ bw) {
    if (blockIdx.x == 0) {
        __shared__ int s[256];
        int t = threadIdx.x;
        int v = (t < nb) ? bsum[t] : 0;
        s[t] = v;
        __syncthreads();
        for (int d = 1; d < 256; d <<= 1) {
            int x = (t >= d) ? s[t - d] : 0;
            __syncthreads();
            s[t] += x;
            __syncthreads();
        }
        if (t < nb) boff[t] = s[t] - v;
        if (t == nb - 1) boff[nb] = s[t];
    } else {
        int idx = (blockIdx.x - 1) * 256 + threadIdx.x;
        if (idx < 96 * 64) {
            int k = idx >> 6, nn = idx & 63;
            float s = 0.0f;
#pragma unroll
            for (int j = 0; j < 96; ++j) s = fmaf(W1[k * 96 + j], W2[j * 64 + nn], s);
            W12[idx] = s;
        } else if (idx < 96 * 64 + 64) {
            int nn = idx - 96 * 64;
            float s = 0.0f;
#pragma unroll
            for (int j = 0; j < 96; ++j) s = fmaf(b1[j], W2[j * 64 + nn], s);
            bw[nn] = s;
        }
    }
}

// ---------------------------------------------------------------------------
// Phase A2: scatter (src,dst) pairs to bucket-major ebuf. Global offset =
// block-local scanned + boff (scan3 folded in).
__global__ void scatterA_kernel(const int* __restrict__ src, const int* __restrict__ dst,
                                const int* __restrict__ scanned, const int* __restrict__ boff,
                                int2* __restrict__ ebuf) {
    __shared__ int off[256];
    {
        int gi = threadIdx.x * NBLKA + blockIdx.x;
        off[threadIdx.x] = scanned[gi] + boff[gi >> 8];
    }
    __syncthreads();
    int base = blockIdx.x * EPB;
    for (int i = base + threadIdx.x; i < base + EPB; i += 256) {
        int s = src[i];
        int d = dst[i];
        int p = atomicAdd(&off[d >> 8], 1);
        ebuf[p] = make_int2(s, d);
    }
}

// ---------------------------------------------------------------------------
// Phase B: one block per 256-node bucket. LDS degree count -> rowstart + dinv,
// then LDS-cursor scatter of esrc (no global atomics).
__global__ void bucket_kernel(const int2* __restrict__ ebuf, const int* __restrict__ scanned,
                              const int* __restrict__ boff, int* __restrict__ rowstart,
                              float* __restrict__ dinv, int* __restrict__ esrc) {
    __shared__ int cnt[256];
    __shared__ int cur[256];
    __shared__ int s[256];
    int k = blockIdx.x;
    int tid = threadIdx.x;
    int i0 = k * NBLKA, i1 = (k + 1) * NBLKA;
    int base = scanned[i0] + boff[i0 >> 8];
    int end  = (k == NBUCK - 1) ? N_EDGES : (scanned[i1] + boff[i1 >> 8]);
    cnt[tid] = 0;
    __syncthreads();
    for (int i = base + tid; i < end; i += 256)
        atomicAdd(&cnt[ebuf[i].y & 255], 1);
    __syncthreads();
    int v = cnt[tid];
    s[tid] = v;
    __syncthreads();
    for (int d = 1; d < 256; d <<= 1) {
        int t = (tid >= d) ? s[tid - d] : 0;
        __syncthreads();
        s[tid] += t;
        __syncthreads();
    }
    int excl = s[tid] - v;
    int node = (k << 8) + tid;
    cur[tid] = base + excl;
    if (node < N_NODES) {
        rowstart[node] = base + excl;
        dinv[node] = rsqrtf((float)v + 1.0f);
    }
    if (k == 0 && tid == 0) rowstart[N_NODES] = N_EDGES;
    __syncthreads();
    for (int i = base + tid; i < end; i += 256) {
        int2 e = ebuf[i];
        int p = atomicAdd(&cur[e.y & 255], 1);
        esrc[p] = e.x;
    }
}

// ---------------------------------------------------------------------------
// y[M,64] = A[M,96] @ W[96,64]. Register-tiled, LDS-only inner loop.
// __launch_bounds__(256): default 1024-thread budget caps VGPR at 64 -> spill.
// #pragma unroll 1: full unroll hoists 24x8 LDS reads -> ~770 live regs -> spill.
#define FMA4(ACC, SCL, WV)                                                     \
    ACC.x = fmaf(SCL, WV.x, ACC.x);                                            \
    ACC.y = fmaf(SCL, WV.y, ACC.y);                                            \
    ACC.z = fmaf(SCL, WV.z, ACC.z);                                            \
    ACC.w = fmaf(SCL, WV.w, ACC.w);

__global__ __launch_bounds__(256)
void gemm_kernel(const float* __restrict__ A, const float* __restrict__ W,
                 float* __restrict__ out, int M) {
    __shared__ float sW[96 * 64];     // [k][col]
    __shared__ float sA[64 * 100];    // [row][k], padded stride 100
    int tid = threadIdx.x;

    {   // stage W (coalesced float4)
        const float4* W4 = (const float4*)W;
        float4* sW4 = (float4*)sW;
        for (int i = tid; i < 96 * 16; i += 256) sW4[i] = W4[i];
    }
    long row0 = (long)blockIdx.x * 64;
    {   // stage A rows (coalesced float4; clamp for tail block)
        const float4* A4 = (const float4*)A;
        long base4 = row0 * 24;
        long lim = (long)M * 24 - 1;
        for (int f = tid; f < 64 * 24; f += 256) {
            long g = base4 + f;
            if (g > lim) g = lim;
            float4 v = A4[g];
            int r = f / 24, kc = f - r * 24;
            *(float4*)(sA + r * 100 + kc * 4) = v;
        }
    }
    __syncthreads();

    int tx = tid & 15;
    int ty = tid >> 4;
    float4 acc0 = {0, 0, 0, 0};
    float4 acc1 = {0, 0, 0, 0};
    float4 acc2 = {0, 0, 0, 0};
    float4 acc3 = {0, 0, 0, 0};
    const float* pa = sA + ty * 4 * 100;
    const float* pw = sW + tx * 4;

#pragma unroll 1
    for (int k = 0; k < 96; k += 4) {
        float4 a0 = *(const float4*)(pa + 0 * 100 + k);
        float4 a1 = *(const float4*)(pa + 1 * 100 + k);
        float4 a2 = *(const float4*)(pa + 2 * 100 + k);
        float4 a3 = *(const float4*)(pa + 3 * 100 + k);
        float4 w0 = *(const float4*)(pw + (k + 0) * 64);
        float4 w1 = *(const float4*)(pw + (k + 1) * 64);
        float4 w2 = *(const float4*)(pw + (k + 2) * 64);
        float4 w3 = *(const float4*)(pw + (k + 3) * 64);
        FMA4(acc0, a0.x, w0) FMA4(acc0, a0.y, w1) FMA4(acc0, a0.z, w2) FMA4(acc0, a0.w, w3)
        FMA4(acc1, a1.x, w0) FMA4(acc1, a1.y, w1) FMA4(acc1, a1.z, w2) FMA4(acc1, a1.w, w3)
        FMA4(acc2, a2.x, w0) FMA4(acc2, a2.y, w1) FMA4(acc2, a2.z, w2) FMA4(acc2, a2.w, w3)
        FMA4(acc3, a3.x, w0) FMA4(acc3, a3.y, w1) FMA4(acc3, a3.z, w2) FMA4(acc3, a3.w, w3)
    }

    long r0 = row0 + ty * 4;
    if (r0 + 0 < M) *(float4*)(out + (r0 + 0) * 64 + tx * 4) = acc0;
    if (r0 + 1 < M) *(float4*)(out + (r0 + 1) * 64 + tx * 4) = acc1;
    if (r0 + 2 < M) *(float4*)(out + (r0 + 2) * 64 + tx * 4) = acc2;
    if (r0 + 3 < M) *(float4*)(out + (r0 + 3) * 64 + tx * 4) = acc3;
}

// ---------------------------------------------------------------------------
// Aggregation, float4-gather layout: wave = 4 edge-subslots x 16 lanes.
// Lane l: sub = l>>4 (which edge in a 4-edge step), f4 = (l&15)*4 (features).
// One dwordx4 VMEM instruction fetches FOUR y-rows (1KB) -> 4x fewer loads
// and bpermutes per edge; 4-step unroll keeps 16 edges in flight.
// Zero-padded (sj=0,dj=0) group entries make over-run steps contribute 0.
template <bool FINAL>
__global__ __launch_bounds__(256)
void agg_kernel(const float* __restrict__ y, const int* __restrict__ rowstart,
                const int* __restrict__ esrc, const float* __restrict__ dinv,
                const float* __restrict__ bw, const float* __restrict__ b2,
                float* __restrict__ out, int n) {
    int wid = (blockIdx.x * blockDim.x + threadIdx.x) >> 6;
    int lane = threadIdx.x & 63;
    if (wid >= n) return;
    int rs = rowstart[wid];
    int re = rowstart[wid + 1];
    float di = dinv[wid];
    int sub = lane >> 4;
    int f4 = (lane & 15) * 4;
    float4 A0 = {0, 0, 0, 0};
    float4 A1 = {0, 0, 0, 0};
    float4 A2 = {0, 0, 0, 0};
    float4 A3 = {0, 0, 0, 0};
    float sd = 0.0f;

    for (int base = rs; base < re; base += 64) {
        int idx = base + lane;
        bool ok = idx < re;
        int sj = ok ? esrc[idx] : 0;
        float dj = ok ? dinv[sj] : 0.0f;
        sd += dj;
        int nn = re - base;
        if (nn > 64) nn = 64;
#pragma unroll 1
        for (int st = 0; st * 4 < nn; st += 4) {
            int e0 = (st + 0) * 4 + sub;
            int e1 = (st + 1) * 4 + sub;
            int e2 = (st + 2) * 4 + sub;
            int e3 = (st + 3) * 4 + sub;
            int s0 = __shfl(sj, e0); float c0 = __shfl(dj, e0);
            int s1 = __shfl(sj, e1); float c1 = __shfl(dj, e1);
            int s2 = __shfl(sj, e2); float c2 = __shfl(dj, e2);
            int s3 = __shfl(sj, e3); float c3 = __shfl(dj, e3);
            float4 v0 = *(const float4*)(y + (long)s0 * 64 + f4);
            float4 v1 = *(const float4*)(y + (long)s1 * 64 + f4);
            float4 v2 = *(const float4*)(y + (long)s2 * 64 + f4);
            float4 v3 = *(const float4*)(y + (long)s3 * 64 + f4);
            FMA4(A0, c0, v0)
            FMA4(A1, c1, v1)
            FMA4(A2, c2, v2)
            FMA4(A3, c3, v3)
        }
    }

    // combine step accumulators, then fold the 4 subslots (butterfly 16,32)
    float4 es;
    es.x = (A0.x + A1.x) + (A2.x + A3.x);
    es.y = (A0.y + A1.y) + (A2.y + A3.y);
    es.z = (A0.z + A1.z) + (A2.z + A3.z);
    es.w = (A0.w + A1.w) + (A2.w + A3.w);
    es.x += __shfl_xor(es.x, 16); es.x += __shfl_xor(es.x, 32);
    es.y += __shfl_xor(es.y, 16); es.y += __shfl_xor(es.y, 32);
    es.z += __shfl_xor(es.z, 16); es.z += __shfl_xor(es.z, 32);
    es.w += __shfl_xor(es.w, 16); es.w += __shfl_xor(es.w, 32);

    float4 self = *(const float4*)(y + (long)wid * 64 + f4);
    float dii = di * di;
    float4 acc;
    acc.x = fmaf(es.x, di, self.x * dii);
    acc.y = fmaf(es.y, di, self.y * dii);
    acc.z = fmaf(es.z, di, self.z * dii);
    acc.w = fmaf(es.w, di, self.w * dii);

    if (FINAL) {
#pragma unroll
        for (int m = 1; m < 64; m <<= 1) sd += __shfl_xor(sd, m);
        float si = di * (di + sd);
        float4 bwv = *(const float4*)(bw + f4);
        float4 b2v = *(const float4*)(b2 + f4);
        acc.x = fmaf(si, bwv.x, acc.x) + b2v.x;
        acc.y = fmaf(si, bwv.y, acc.y) + b2v.y;
        acc.z = fmaf(si, bwv.z, acc.z) + b2v.z;
        acc.w = fmaf(si, bwv.w, acc.w) + b2v.w;
    }
    if (lane < 16) *(float4*)(out + (long)wid * 64 + f4) = acc;
}

// ---------------------------------------------------------------------------
extern "C" void kernel_launch(void* const* d_in, const int* in_sizes, int n_in,
                              void* d_out, int out_size, void* d_ws, size_t ws_size,
                              hipStream_t stream) {
    const float* x  = (const float*)d_in[0];
    const int*   ei = (const int*)d_in[1];
    const float* W1 = (const float*)d_in[2];
    const float* b1 = (const float*)d_in[3];
    const float* W2 = (const float*)d_in[4];
    const float* b2 = (const float*)d_in[5];
    float* out = (float*)d_out;

    const int* src = ei;
    const int* dst = ei + N_EDGES;

    // workspace layout (bytes); ebuf aliases z (disjoint lifetimes)
    char* ws = (char*)d_ws;
    float* dinv     = (float*)(ws + 0);                  // 204800
    int*   rowstart = (int*)  (ws + 204800);             // 200004 -> pad 204800
    int*   hist     = (int*)  (ws + 409600);             // 204800 (51200 ints)
    int*   scanned  = (int*)  (ws + 614400);             // 204800 (block-local)
    int*   bsum     = (int*)  (ws + 823296);             // 1024
    int*   boff     = (int*)  (ws + 824320);             // 1024
    float* W12      = (float*)(ws + 825344);             // 24576
    float* bw       = (float*)(ws + 849920);             // 512
    int*   esrc     = (int*)  (ws + 850432);             // 3200000
    float* y        = (float*)(ws + 4050432);            // 12800000
    int2*  ebuf     = (int2*) (ws + 16850432);           // 6400000 (aliases z)
    float* z        = (float*)(ws + 16850432);           // 12800000 (end 29.65MB)

    // Phase A: bucket edges by dst>>8 with full-line writes
    histA_kernel<<<NBLKA, 256, 0, stream>>>(dst, hist);
    scan1_kernel<<<MSCAN / 256, 256, 0, stream>>>(hist, scanned, bsum, MSCAN);
    scan2_wfuse_kernel<<<26, 256, 0, stream>>>(bsum, boff, MSCAN / 256,
                                               W1, W2, b1, W12, bw);
    scatterA_kernel<<<NBLKA, 256, 0, stream>>>(src, dst, scanned, boff, ebuf);

    // Phase B: per-bucket degree count + rowstart + dinv + LDS-cursor scatter
    bucket_kernel<<<NBUCK, 256, 0, stream>>>(ebuf, scanned, boff, rowstart, dinv, esrc);

    // single fused GEMM (W12 produced alongside scan2)
    gemm_kernel<<<(N_NODES + 63) / 64, 256, 0, stream>>>(x, W12, y, N_NODES);

    // two aggregation passes: z = N y ; out = N z + s*bw + b2
    int aggBlocks = (N_NODES + 3) / 4;  // one 64-lane wave per node, 4 waves/block
    agg_kernel<false><<<aggBlocks, 256, 0, stream>>>(y, rowstart, esrc, dinv, bw, b2, z, N_NODES);
    agg_kernel<true><<<aggBlocks, 256, 0, stream>>>(z, rowstart, esrc, dinv, bw, b2, out, N_NODES);
}

// Round 13
// 98.974 us; speedup vs baseline: 5.1653x; 1.1436x over previous
//
#include <hip/hip_runtime.h>

#define N_NODES 50000
#define N_EDGES 800000
#define NBLKA 200                 // Phase-A blocks; 800000/200 = 4000 edges each
#define EPB (N_EDGES / NBLKA)     // 4000
#define NBUCK 196                 // ceil(50000/256) buckets of 256 nodes
#define MSCAN (256 * NBLKA)       // 51200 hist entries to scan
#define GEMMBLKS ((N_NODES + 63) / 64)   // 782

typedef unsigned int uint;
typedef unsigned short ushort;

// f32 -> bf16 RTNE pack of two values into one uint
__device__ __forceinline__ uint bf16pack(float a, float b) {
    uint ua = __float_as_uint(a); ua = (ua + 0x7FFFu + ((ua >> 16) & 1u)) >> 16;
    uint ub = __float_as_uint(b); ub = (ub + 0x7FFFu + ((ub >> 16) & 1u)) >> 16;
    return ua | (ub << 16);
}
#define BF_LO(U) __uint_as_float((U) << 16)
#define BF_HI(U) __uint_as_float((U) & 0xFFFF0000u)

// ---------------------------------------------------------------------------
// Phase A1: per-block 256-bin histogram of dst>>8, bin-major global layout
__global__ void histA_kernel(const int* __restrict__ dst, int* __restrict__ hist) {
    __shared__ int h[256];
    h[threadIdx.x] = 0;
    __syncthreads();
    int base = blockIdx.x * EPB;
    for (int i = base + threadIdx.x; i < base + EPB; i += 256)
        atomicAdd(&h[dst[i] >> 8], 1);
    __syncthreads();
    hist[threadIdx.x * NBLKA + blockIdx.x] = h[threadIdx.x];
}

// ---------------------------------------------------------------------------
// scan1: block-local exclusive scan of hist -> scanned (local), bsum per block
__global__ void scan1_kernel(const int* __restrict__ in, int* __restrict__ out,
                             int* __restrict__ bsum, int n) {
    __shared__ int s[256];
    int i = blockIdx.x * 256 + threadIdx.x;
    int v = (i < n) ? in[i] : 0;
    s[threadIdx.x] = v;
    __syncthreads();
    for (int d = 1; d < 256; d <<= 1) {
        int t = (threadIdx.x >= d) ? s[threadIdx.x - d] : 0;
        __syncthreads();
        s[threadIdx.x] += t;
        __syncthreads();
    }
    if (i < n) out[i] = s[threadIdx.x] - v;
    if (threadIdx.x == 255) bsum[blockIdx.x] = s[255];
}

// scan2 (block 0) + wfuse (blocks 1..25) merged.
__global__ void scan2_wfuse_kernel(int* __restrict__ bsum, int* __restrict__ boff, int nb,
                                   const float* __restrict__ W1, const float* __restrict__ W2,
                                   const float* __restrict__ b1, float* __restrict__ W12,
                                   float* __restrict__ bw) {
    if (blockIdx.x == 0) {
        __shared__ int s[256];
        int t = threadIdx.x;
        int v = (t < nb) ? bsum[t] : 0;
        s[t] = v;
        __syncthreads();
        for (int d = 1; d < 256; d <<= 1) {
            int x = (t >= d) ? s[t - d] : 0;
            __syncthreads();
            s[t] += x;
            __syncthreads();
        }
        if (t < nb) boff[t] = s[t] - v;
        if (t == nb - 1) boff[nb] = s[t];
    } else {
        int idx = (blockIdx.x - 1) * 256 + threadIdx.x;
        if (idx < 96 * 64) {
            int k = idx >> 6, nn = idx & 63;
            float s = 0.0f;
#pragma unroll
            for (int j = 0; j < 96; ++j) s = fmaf(W1[k * 96 + j], W2[j * 64 + nn], s);
            W12[idx] = s;
        } else if (idx < 96 * 64 + 64) {
            int nn = idx - 96 * 64;
            float s = 0.0f;
#pragma unroll
            for (int j = 0; j < 96; ++j) s = fmaf(b1[j], W2[j * 64 + nn], s);
            bw[nn] = s;
        }
    }
}

// ---------------------------------------------------------------------------
// Merged Phase A2 scatter (blocks 0..NBLKA-1) + GEMM (blocks NBLKA..).
// Independent work: scatter needs scanned/boff; gemm needs W12 (ready).
// gemm: y16[M,64](bf16) = A[M,96] @ W[96,64], register-tiled, LDS staged.
#define FMA4(ACC, SCL, WV)                                                     \
    ACC.x = fmaf(SCL, WV.x, ACC.x);                                            \
    ACC.y = fmaf(SCL, WV.y, ACC.y);                                            \
    ACC.z = fmaf(SCL, WV.z, ACC.z);                                            \
    ACC.w = fmaf(SCL, WV.w, ACC.w);

__global__ __launch_bounds__(256)
void scatter_gemm_kernel(const int* __restrict__ src, const int* __restrict__ dst,
                         const int* __restrict__ scanned, const int* __restrict__ boff,
                         int2* __restrict__ ebuf,
                         const float* __restrict__ A, const float* __restrict__ W,
                         ushort* __restrict__ y16, int M) {
    __shared__ float smem[96 * 64 + 64 * 100];   // gemm: sW + sA; scatter: off
    int tid = threadIdx.x;

    if (blockIdx.x < NBLKA) {
        int* off = (int*)smem;
        int gi = tid * NBLKA + blockIdx.x;
        off[tid] = scanned[gi] + boff[gi >> 8];
        __syncthreads();
        int base = blockIdx.x * EPB;
        for (int i = base + tid; i < base + EPB; i += 256) {
            int s = src[i];
            int d = dst[i];
            int p = atomicAdd(&off[d >> 8], 1);
            ebuf[p] = make_int2(s, d);
        }
        return;
    }

    int bid = blockIdx.x - NBLKA;
    float* sW = smem;
    float* sA = smem + 96 * 64;
    {   // stage W (coalesced float4)
        const float4* W4 = (const float4*)W;
        float4* sW4 = (float4*)sW;
        for (int i = tid; i < 96 * 16; i += 256) sW4[i] = W4[i];
    }
    long row0 = (long)bid * 64;
    {   // stage A rows (coalesced float4; clamp for tail block)
        const float4* A4 = (const float4*)A;
        long base4 = row0 * 24;
        long lim = (long)M * 24 - 1;
        for (int f = tid; f < 64 * 24; f += 256) {
            long g = base4 + f;
            if (g > lim) g = lim;
            float4 v = A4[g];
            int r = f / 24, kc = f - r * 24;
            *(float4*)(sA + r * 100 + kc * 4) = v;
        }
    }
    __syncthreads();

    int tx = tid & 15;
    int ty = tid >> 4;
    float4 acc0 = {0, 0, 0, 0};
    float4 acc1 = {0, 0, 0, 0};
    float4 acc2 = {0, 0, 0, 0};
    float4 acc3 = {0, 0, 0, 0};
    const float* pa = sA + ty * 4 * 100;
    const float* pw = sW + tx * 4;

#pragma unroll 1
    for (int k = 0; k < 96; k += 4) {
        float4 a0 = *(const float4*)(pa + 0 * 100 + k);
        float4 a1 = *(const float4*)(pa + 1 * 100 + k);
        float4 a2 = *(const float4*)(pa + 2 * 100 + k);
        float4 a3 = *(const float4*)(pa + 3 * 100 + k);
        float4 w0 = *(const float4*)(pw + (k + 0) * 64);
        float4 w1 = *(const float4*)(pw + (k + 1) * 64);
        float4 w2 = *(const float4*)(pw + (k + 2) * 64);
        float4 w3 = *(const float4*)(pw + (k + 3) * 64);
        FMA4(acc0, a0.x, w0) FMA4(acc0, a0.y, w1) FMA4(acc0, a0.z, w2) FMA4(acc0, a0.w, w3)
        FMA4(acc1, a1.x, w0) FMA4(acc1, a1.y, w1) FMA4(acc1, a1.z, w2) FMA4(acc1, a1.w, w3)
        FMA4(acc2, a2.x, w0) FMA4(acc2, a2.y, w1) FMA4(acc2, a2.z, w2) FMA4(acc2, a2.w, w3)
        FMA4(acc3, a3.x, w0) FMA4(acc3, a3.y, w1) FMA4(acc3, a3.z, w2) FMA4(acc3, a3.w, w3)
    }

    long r0 = row0 + ty * 4;
    uint2 p0 = {bf16pack(acc0.x, acc0.y), bf16pack(acc0.z, acc0.w)};
    uint2 p1 = {bf16pack(acc1.x, acc1.y), bf16pack(acc1.z, acc1.w)};
    uint2 p2 = {bf16pack(acc2.x, acc2.y), bf16pack(acc2.z, acc2.w)};
    uint2 p3 = {bf16pack(acc3.x, acc3.y), bf16pack(acc3.z, acc3.w)};
    if (r0 + 0 < M) *(uint2*)(y16 + (r0 + 0) * 64 + tx * 4) = p0;
    if (r0 + 1 < M) *(uint2*)(y16 + (r0 + 1) * 64 + tx * 4) = p1;
    if (r0 + 2 < M) *(uint2*)(y16 + (r0 + 2) * 64 + tx * 4) = p2;
    if (r0 + 3 < M) *(uint2*)(y16 + (r0 + 3) * 64 + tx * 4) = p3;
}

// ---------------------------------------------------------------------------
// Phase B: one block per 256-node bucket. LDS degree count -> rowstart + dinv,
// then LDS-cursor scatter of esrc (no global atomics).
__global__ void bucket_kernel(const int2* __restrict__ ebuf, const int* __restrict__ scanned,
                              const int* __restrict__ boff, int* __restrict__ rowstart,
                              float* __restrict__ dinv, int* __restrict__ esrc) {
    __shared__ int cnt[256];
    __shared__ int cur[256];
    __shared__ int s[256];
    int k = blockIdx.x;
    int tid = threadIdx.x;
    int i0 = k * NBLKA, i1 = (k + 1) * NBLKA;
    int base = scanned[i0] + boff[i0 >> 8];
    int end  = (k == NBUCK - 1) ? N_EDGES : (scanned[i1] + boff[i1 >> 8]);
    cnt[tid] = 0;
    __syncthreads();
    for (int i = base + tid; i < end; i += 256)
        atomicAdd(&cnt[ebuf[i].y & 255], 1);
    __syncthreads();
    int v = cnt[tid];
    s[tid] = v;
    __syncthreads();
    for (int d = 1; d < 256; d <<= 1) {
        int t = (tid >= d) ? s[tid - d] : 0;
        __syncthreads();
        s[tid] += t;
        __syncthreads();
    }
    int excl = s[tid] - v;
    int node = (k << 8) + tid;
    cur[tid] = base + excl;
    if (node < N_NODES) {
        rowstart[node] = base + excl;
        dinv[node] = rsqrtf((float)v + 1.0f);
    }
    if (k == 0 && tid == 0) rowstart[N_NODES] = N_EDGES;
    __syncthreads();
    for (int i = base + tid; i < end; i += 256) {
        int2 e = ebuf[i];
        int p = atomicAdd(&cur[e.y & 255], 1);
        esrc[p] = e.x;
    }
}

// ---------------------------------------------------------------------------
// Aggregation over bf16 rows (128B each). Wave = 8 edge-subslots x 8 lanes.
// Lane l: sub = l>>3, q = l&7 (uint4 index = features q*8..q*8+7).
// One dwordx4 gather fetches EIGHT rows (1KB). f32 accumulation.
// Pass1 (FINAL=false): zout bf16 = N*y.  Pass2 (FINAL=true): fout f32 =
// N*z + si*bw + b2.  Padded lanes carry dj=0 -> contribute 0.
#define DECFMA(A0, A1, A2, A3, A4, A5, A6, A7, C, V)                           \
    A0 = fmaf(BF_LO(V.x), C, A0); A1 = fmaf(BF_HI(V.x), C, A1);                \
    A2 = fmaf(BF_LO(V.y), C, A2); A3 = fmaf(BF_HI(V.y), C, A3);                \
    A4 = fmaf(BF_LO(V.z), C, A4); A5 = fmaf(BF_HI(V.z), C, A5);                \
    A6 = fmaf(BF_LO(V.w), C, A6); A7 = fmaf(BF_HI(V.w), C, A7);

template <bool FINAL>
__global__ __launch_bounds__(256)
void agg_kernel(const ushort* __restrict__ yin, const int* __restrict__ rowstart,
                const int* __restrict__ esrc, const float* __restrict__ dinv,
                const float* __restrict__ bw, const float* __restrict__ b2,
                ushort* __restrict__ zout, float* __restrict__ fout, int n) {
    int wid = (blockIdx.x * blockDim.x + threadIdx.x) >> 6;
    int lane = threadIdx.x & 63;
    if (wid >= n) return;
    int rs = rowstart[wid];
    int re = rowstart[wid + 1];
    float di = dinv[wid];
    int sub = lane >> 3;
    int q = lane & 7;
    const uint4* yrow = (const uint4*)yin;
    float P0 = 0, P1 = 0, P2 = 0, P3 = 0, P4 = 0, P5 = 0, P6 = 0, P7 = 0;
    float Q0 = 0, Q1 = 0, Q2 = 0, Q3 = 0, Q4 = 0, Q5 = 0, Q6 = 0, Q7 = 0;
    float sd = 0.0f;

    for (int base = rs; base < re; base += 64) {
        int idx = base + lane;
        bool ok = idx < re;
        int sj = ok ? esrc[idx] : 0;
        float dj = ok ? dinv[sj] : 0.0f;
        sd += dj;
        int nn = re - base;
        if (nn > 64) nn = 64;
#pragma unroll 1
        for (int it = 0; it * 32 < nn; ++it) {
            int e0 = it * 32 + sub;
            int s0 = __shfl(sj, e0);      float c0 = __shfl(dj, e0);
            int s1 = __shfl(sj, e0 + 8);  float c1 = __shfl(dj, e0 + 8);
            int s2 = __shfl(sj, e0 + 16); float c2 = __shfl(dj, e0 + 16);
            int s3 = __shfl(sj, e0 + 24); float c3 = __shfl(dj, e0 + 24);
            uint4 v0 = yrow[(long)s0 * 8 + q];
            uint4 v1 = yrow[(long)s1 * 8 + q];
            uint4 v2 = yrow[(long)s2 * 8 + q];
            uint4 v3 = yrow[(long)s3 * 8 + q];
            DECFMA(P0, P1, P2, P3, P4, P5, P6, P7, c0, v0)
            DECFMA(Q0, Q1, Q2, Q3, Q4, Q5, Q6, Q7, c1, v1)
            DECFMA(P0, P1, P2, P3, P4, P5, P6, P7, c2, v2)
            DECFMA(Q0, Q1, Q2, Q3, Q4, Q5, Q6, Q7, c3, v3)
        }
    }

    float t0 = P0 + Q0, t1 = P1 + Q1, t2 = P2 + Q2, t3 = P3 + Q3;
    float t4 = P4 + Q4, t5 = P5 + Q5, t6 = P6 + Q6, t7 = P7 + Q7;
    // fold the 8 subslots: lanes {l, l^8, l^16, l^32} share q
    t0 += __shfl_xor(t0, 8); t0 += __shfl_xor(t0, 16); t0 += __shfl_xor(t0, 32);
    t1 += __shfl_xor(t1, 8); t1 += __shfl_xor(t1, 16); t1 += __shfl_xor(t1, 32);
    t2 += __shfl_xor(t2, 8); t2 += __shfl_xor(t2, 16); t2 += __shfl_xor(t2, 32);
    t3 += __shfl_xor(t3, 8); t3 += __shfl_xor(t3, 16); t3 += __shfl_xor(t3, 32);
    t4 += __shfl_xor(t4, 8); t4 += __shfl_xor(t4, 16); t4 += __shfl_xor(t4, 32);
    t5 += __shfl_xor(t5, 8); t5 += __shfl_xor(t5, 16); t5 += __shfl_xor(t5, 32);
    t6 += __shfl_xor(t6, 8); t6 += __shfl_xor(t6, 16); t6 += __shfl_xor(t6, 32);
    t7 += __shfl_xor(t7, 8); t7 += __shfl_xor(t7, 16); t7 += __shfl_xor(t7, 32);

    // self term
    uint4 sv = yrow[(long)wid * 8 + q];
    float dii = di * di;
    float o0 = fmaf(t0, di, BF_LO(sv.x) * dii);
    float o1 = fmaf(t1, di, BF_HI(sv.x) * dii);
    float o2 = fmaf(t2, di, BF_LO(sv.y) * dii);
    float o3 = fmaf(t3, di, BF_HI(sv.y) * dii);
    float o4 = fmaf(t4, di, BF_LO(sv.z) * dii);
    float o5 = fmaf(t5, di, BF_HI(sv.z) * dii);
    float o6 = fmaf(t6, di, BF_LO(sv.w) * dii);
    float o7 = fmaf(t7, di, BF_HI(sv.w) * dii);

    if (FINAL) {
#pragma unroll
        for (int m = 1; m < 64; m <<= 1) sd += __shfl_xor(sd, m);
        float si = di * (di + sd);
        int fo = q * 8;
        float4 bwa = *(const float4*)(bw + fo);
        float4 bwb = *(const float4*)(bw + fo + 4);
        float4 b2a = *(const float4*)(b2 + fo);
        float4 b2b = *(const float4*)(b2 + fo + 4);
        o0 = fmaf(si, bwa.x, o0) + b2a.x;
        o1 = fmaf(si, bwa.y, o1) + b2a.y;
        o2 = fmaf(si, bwa.z, o2) + b2a.z;
        o3 = fmaf(si, bwa.w, o3) + b2a.w;
        o4 = fmaf(si, bwb.x, o4) + b2b.x;
        o5 = fmaf(si, bwb.y, o5) + b2b.y;
        o6 = fmaf(si, bwb.z, o6) + b2b.z;
        o7 = fmaf(si, bwb.w, o7) + b2b.w;
        if (sub == 0) {
            float4 wa = {o0, o1, o2, o3};
            float4 wb = {o4, o5, o6, o7};
            *(float4*)(fout + (long)wid * 64 + q * 8) = wa;
            *(float4*)(fout + (long)wid * 64 + q * 8 + 4) = wb;
        }
    } else {
        if (sub == 0) {
            uint4 pk;
            pk.x = bf16pack(o0, o1);
            pk.y = bf16pack(o2, o3);
            pk.z = bf16pack(o4, o5);
            pk.w = bf16pack(o6, o7);
            *(uint4*)(zout + (long)wid * 64 + q * 8) = pk;
        }
    }
}

// ---------------------------------------------------------------------------
extern "C" void kernel_launch(void* const* d_in, const int* in_sizes, int n_in,
                              void* d_out, int out_size, void* d_ws, size_t ws_size,
                              hipStream_t stream) {
    const float* x  = (const float*)d_in[0];
    const int*   ei = (const int*)d_in[1];
    const float* W1 = (const float*)d_in[2];
    const float* b1 = (const float*)d_in[3];
    const float* W2 = (const float*)d_in[4];
    const float* b2 = (const float*)d_in[5];
    float* out = (float*)d_out;

    const int* src = ei;
    const int* dst = ei + N_EDGES;

    // workspace layout (bytes); z16 aliases ebuf (ebuf dead after bucket)
    char* ws = (char*)d_ws;
    float*  dinv     = (float*) (ws + 0);                // 204800
    int*    rowstart = (int*)   (ws + 204800);           // 204800 (n+1)
    int*    hist     = (int*)   (ws + 409600);           // 204800
    int*    scanned  = (int*)   (ws + 614400);           // 204800 (block-local)
    int*    bsum     = (int*)   (ws + 823296);           // 1024
    int*    boff     = (int*)   (ws + 824320);           // 1024
    float*  W12      = (float*) (ws + 825344);           // 24576
    float*  bw       = (float*) (ws + 849920);           // 512
    int*    esrc     = (int*)   (ws + 850432);           // 3200000 -> 4050432
    ushort* y16      = (ushort*)(ws + 4050432);          // 6400000 -> 10450432
    int2*   ebuf     = (int2*)  (ws + 10450432);         // 6400000 -> 16850432
    ushort* z16      = (ushort*)(ws + 10450432);         // aliases ebuf

    // Phase A: bucket edges by dst>>8 (full-line writes)
    histA_kernel<<<NBLKA, 256, 0, stream>>>(dst, hist);
    scan1_kernel<<<MSCAN / 256, 256, 0, stream>>>(hist, scanned, bsum, MSCAN);
    scan2_wfuse_kernel<<<26, 256, 0, stream>>>(bsum, boff, MSCAN / 256,
                                               W1, W2, b1, W12, bw);
    // scatter (blocks 0..199) || gemm y16 = x @ W12 (blocks 200..981)
    scatter_gemm_kernel<<<NBLKA + GEMMBLKS, 256, 0, stream>>>(
        src, dst, scanned, boff, ebuf, x, W12, y16, N_NODES);

    // Phase B: per-bucket rowstart + dinv + LDS-cursor scatter of esrc
    bucket_kernel<<<NBUCK, 256, 0, stream>>>(ebuf, scanned, boff, rowstart, dinv, esrc);

    // two aggregation passes: z16 = N y16 ; out = N z16 + si*bw + b2
    int aggBlocks = (N_NODES + 3) / 4;   // one 64-lane wave per node
    agg_kernel<false><<<aggBlocks, 256, 0, stream>>>(y16, rowstart, esrc, dinv,
                                                     bw, b2, z16, out, N_NODES);
    agg_kernel<true><<<aggBlocks, 256, 0, stream>>>(z16, rowstart, esrc, dinv,
                                                    bw, b2, z16, out, N_NODES);
}

// Round 14
// 86.142 us; speedup vs baseline: 5.9347x; 1.1490x over previous
//
#include <hip/hip_runtime.h>

#define N_NODES 50000
#define N_EDGES 800000
#define NBLKA 200                 // Phase-A blocks; 800000/200 = 4000 edges each
#define EPB (N_EDGES / NBLKA)     // 4000
#define NBUCK 196                 // ceil(50000/256) buckets of 256 nodes
#define MSCAN (256 * NBLKA)       // 51200 hist entries to scan
#define GEMMBLKS ((N_NODES + 63) / 64)   // 782

typedef unsigned int uint;
typedef unsigned short ushort;

// f32 -> bf16 RTNE pack of two values into one uint
__device__ __forceinline__ uint bf16pack(float a, float b) {
    uint ua = __float_as_uint(a); ua = (ua + 0x7FFFu + ((ua >> 16) & 1u)) >> 16;
    uint ub = __float_as_uint(b); ub = (ub + 0x7FFFu + ((ub >> 16) & 1u)) >> 16;
    return ua | (ub << 16);
}
#define BF_LO(U) __uint_as_float((U) << 16)
#define BF_HI(U) __uint_as_float((U) & 0xFFFF0000u)

// ---------------------------------------------------------------------------
// Phase A1: per-block 256-bin histogram of dst>>8, bin-major global layout
__global__ void histA_kernel(const int* __restrict__ dst, int* __restrict__ hist) {
    __shared__ int h[256];
    h[threadIdx.x] = 0;
    __syncthreads();
    int base = blockIdx.x * EPB;
    for (int i = base + threadIdx.x; i < base + EPB; i += 256)
        atomicAdd(&h[dst[i] >> 8], 1);
    __syncthreads();
    hist[threadIdx.x * NBLKA + blockIdx.x] = h[threadIdx.x];
}

// ---------------------------------------------------------------------------
// scan1: block-local exclusive scan of hist -> scanned (local), bsum per block
__global__ void scan1_kernel(const int* __restrict__ in, int* __restrict__ out,
                             int* __restrict__ bsum, int n) {
    __shared__ int s[256];
    int i = blockIdx.x * 256 + threadIdx.x;
    int v = (i < n) ? in[i] : 0;
    s[threadIdx.x] = v;
    __syncthreads();
    for (int d = 1; d < 256; d <<= 1) {
        int t = (threadIdx.x >= d) ? s[threadIdx.x - d] : 0;
        __syncthreads();
        s[threadIdx.x] += t;
        __syncthreads();
    }
    if (i < n) out[i] = s[threadIdx.x] - v;
    if (threadIdx.x == 255) bsum[blockIdx.x] = s[255];
}

// scan2 (block 0) + wfuse (blocks 1..25) merged.
__global__ void scan2_wfuse_kernel(int* __restrict__ bsum, int* __restrict__ boff, int nb,
                                   const float* __restrict__ W1, const float* __restrict__ W2,
                                   const float* __restrict__ b1, float* __restrict__ W12,
                                   float* __restrict__ bw) {
    if (blockIdx.x == 0) {
        __shared__ int s[256];
        int t = threadIdx.x;
        int v = (t < nb) ? bsum[t] : 0;
        s[t] = v;
        __syncthreads();
        for (int d = 1; d < 256; d <<= 1) {
            int x = (t >= d) ? s[t - d] : 0;
            __syncthreads();
            s[t] += x;
            __syncthreads();
        }
        if (t < nb) boff[t] = s[t] - v;
        if (t == nb - 1) boff[nb] = s[t];
    } else {
        int idx = (blockIdx.x - 1) * 256 + threadIdx.x;
        if (idx < 96 * 64) {
            int k = idx >> 6, nn = idx & 63;
            float s = 0.0f;
#pragma unroll
            for (int j = 0; j < 96; ++j) s = fmaf(W1[k * 96 + j], W2[j * 64 + nn], s);
            W12[idx] = s;
        } else if (idx < 96 * 64 + 64) {
            int nn = idx - 96 * 64;
            float s = 0.0f;
#pragma unroll
            for (int j = 0; j < 96; ++j) s = fmaf(b1[j], W2[j * 64 + nn], s);
            bw[nn] = s;
        }
    }
}

// ---------------------------------------------------------------------------
// Merged Phase A2 scatter (blocks 0..NBLKA-1) + GEMM (blocks NBLKA..).
// ebuf entry packed: src(16b) | (dst&255)(8b) -- node ids < 65536.
// gemm: y16[M,64](bf16) = A[M,96] @ W[96,64], register-tiled, LDS staged.
#define FMA4(ACC, SCL, WV)                                                     \
    ACC.x = fmaf(SCL, WV.x, ACC.x);                                            \
    ACC.y = fmaf(SCL, WV.y, ACC.y);                                            \
    ACC.z = fmaf(SCL, WV.z, ACC.z);                                            \
    ACC.w = fmaf(SCL, WV.w, ACC.w);

__global__ __launch_bounds__(256)
void scatter_gemm_kernel(const int* __restrict__ src, const int* __restrict__ dst,
                         const int* __restrict__ scanned, const int* __restrict__ boff,
                         uint* __restrict__ ebuf,
                         const float* __restrict__ A, const float* __restrict__ W,
                         ushort* __restrict__ y16, int M) {
    __shared__ float smem[96 * 64 + 64 * 100];   // gemm: sW + sA; scatter: off
    int tid = threadIdx.x;

    if (blockIdx.x < NBLKA) {
        int* off = (int*)smem;
        int gi = tid * NBLKA + blockIdx.x;
        off[tid] = scanned[gi] + boff[gi >> 8];
        __syncthreads();
        int base = blockIdx.x * EPB;
        for (int i = base + tid; i < base + EPB; i += 256) {
            int s = src[i];
            int d = dst[i];
            int p = atomicAdd(&off[d >> 8], 1);
            ebuf[p] = (uint)s | ((uint)(d & 255) << 16);
        }
        return;
    }

    int bid = blockIdx.x - NBLKA;
    float* sW = smem;
    float* sA = smem + 96 * 64;
    {   // stage W (coalesced float4)
        const float4* W4 = (const float4*)W;
        float4* sW4 = (float4*)sW;
        for (int i = tid; i < 96 * 16; i += 256) sW4[i] = W4[i];
    }
    long row0 = (long)bid * 64;
    {   // stage A rows (coalesced float4; clamp for tail block)
        const float4* A4 = (const float4*)A;
        long base4 = row0 * 24;
        long lim = (long)M * 24 - 1;
        for (int f = tid; f < 64 * 24; f += 256) {
            long g = base4 + f;
            if (g > lim) g = lim;
            float4 v = A4[g];
            int r = f / 24, kc = f - r * 24;
            *(float4*)(sA + r * 100 + kc * 4) = v;
        }
    }
    __syncthreads();

    int tx = tid & 15;
    int ty = tid >> 4;
    float4 acc0 = {0, 0, 0, 0};
    float4 acc1 = {0, 0, 0, 0};
    float4 acc2 = {0, 0, 0, 0};
    float4 acc3 = {0, 0, 0, 0};
    const float* pa = sA + ty * 4 * 100;
    const float* pw = sW + tx * 4;

#pragma unroll 1
    for (int k = 0; k < 96; k += 4) {
        float4 a0 = *(const float4*)(pa + 0 * 100 + k);
        float4 a1 = *(const float4*)(pa + 1 * 100 + k);
        float4 a2 = *(const float4*)(pa + 2 * 100 + k);
        float4 a3 = *(const float4*)(pa + 3 * 100 + k);
        float4 w0 = *(const float4*)(pw + (k + 0) * 64);
        float4 w1 = *(const float4*)(pw + (k + 1) * 64);
        float4 w2 = *(const float4*)(pw + (k + 2) * 64);
        float4 w3 = *(const float4*)(pw + (k + 3) * 64);
        FMA4(acc0, a0.x, w0) FMA4(acc0, a0.y, w1) FMA4(acc0, a0.z, w2) FMA4(acc0, a0.w, w3)
        FMA4(acc1, a1.x, w0) FMA4(acc1, a1.y, w1) FMA4(acc1, a1.z, w2) FMA4(acc1, a1.w, w3)
        FMA4(acc2, a2.x, w0) FMA4(acc2, a2.y, w1) FMA4(acc2, a2.z, w2) FMA4(acc2, a2.w, w3)
        FMA4(acc3, a3.x, w0) FMA4(acc3, a3.y, w1) FMA4(acc3, a3.z, w2) FMA4(acc3, a3.w, w3)
    }

    long r0 = row0 + ty * 4;
    uint2 p0 = {bf16pack(acc0.x, acc0.y), bf16pack(acc0.z, acc0.w)};
    uint2 p1 = {bf16pack(acc1.x, acc1.y), bf16pack(acc1.z, acc1.w)};
    uint2 p2 = {bf16pack(acc2.x, acc2.y), bf16pack(acc2.z, acc2.w)};
    uint2 p3 = {bf16pack(acc3.x, acc3.y), bf16pack(acc3.z, acc3.w)};
    if (r0 + 0 < M) *(uint2*)(y16 + (r0 + 0) * 64 + tx * 4) = p0;
    if (r0 + 1 < M) *(uint2*)(y16 + (r0 + 1) * 64 + tx * 4) = p1;
    if (r0 + 2 < M) *(uint2*)(y16 + (r0 + 2) * 64 + tx * 4) = p2;
    if (r0 + 3 < M) *(uint2*)(y16 + (r0 + 3) * 64 + tx * 4) = p3;
}

// ---------------------------------------------------------------------------
// Phase B: one block per 256-node bucket. LDS degree count -> rowstart + dinv,
// then LDS-cursor scatter of esrc (ushort src ids; no global atomics).
__global__ void bucket_kernel(const uint* __restrict__ ebuf, const int* __restrict__ scanned,
                              const int* __restrict__ boff, int* __restrict__ rowstart,
                              float* __restrict__ dinv, ushort* __restrict__ esrc) {
    __shared__ int cnt[256];
    __shared__ int cur[256];
    __shared__ int s[256];
    int k = blockIdx.x;
    int tid = threadIdx.x;
    int i0 = k * NBLKA, i1 = (k + 1) * NBLKA;
    int base = scanned[i0] + boff[i0 >> 8];
    int end  = (k == NBUCK - 1) ? N_EDGES : (scanned[i1] + boff[i1 >> 8]);
    cnt[tid] = 0;
    __syncthreads();
    for (int i = base + tid; i < end; i += 256)
        atomicAdd(&cnt[(ebuf[i] >> 16) & 255], 1);
    __syncthreads();
    int v = cnt[tid];
    s[tid] = v;
    __syncthreads();
    for (int d = 1; d < 256; d <<= 1) {
        int t = (tid >= d) ? s[tid - d] : 0;
        __syncthreads();
        s[tid] += t;
        __syncthreads();
    }
    int excl = s[tid] - v;
    int node = (k << 8) + tid;
    cur[tid] = base + excl;
    if (node < N_NODES) {
        rowstart[node] = base + excl;
        dinv[node] = rsqrtf((float)v + 1.0f);
    }
    if (k == 0 && tid == 0) rowstart[N_NODES] = N_EDGES;
    __syncthreads();
    for (int i = base + tid; i < end; i += 256) {
        uint e = ebuf[i];
        int p = atomicAdd(&cur[(e >> 16) & 255], 1);
        esrc[p] = (ushort)(e & 0xFFFFu);
    }
}

// ---------------------------------------------------------------------------
// Aggregation over bf16 rows, 16 LANES PER NODE (4 nodes/wave).
// Group = 16 lanes: 2 edge-subslots x 8 feature-lanes (uint4 = 8 bf16 each).
// vs the 64-lane version: 4x fewer waves -> 4x less prologue/epilogue
// (fold is ONE shfl_xor(8) per accumulator instead of three).
// Padded batch lanes carry dj=0 -> contribute 0; f32 accumulation.
#define DECFMA(A0, A1, A2, A3, A4, A5, A6, A7, C, V)                           \
    A0 = fmaf(BF_LO(V.x), C, A0); A1 = fmaf(BF_HI(V.x), C, A1);                \
    A2 = fmaf(BF_LO(V.y), C, A2); A3 = fmaf(BF_HI(V.y), C, A3);                \
    A4 = fmaf(BF_LO(V.z), C, A4); A5 = fmaf(BF_HI(V.z), C, A5);                \
    A6 = fmaf(BF_LO(V.w), C, A6); A7 = fmaf(BF_HI(V.w), C, A7);

template <bool FINAL>
__global__ __launch_bounds__(256)
void agg_kernel(const ushort* __restrict__ yin, const int* __restrict__ rowstart,
                const ushort* __restrict__ esrc, const float* __restrict__ dinv,
                const float* __restrict__ bw, const float* __restrict__ b2,
                ushort* __restrict__ zout, float* __restrict__ fout, int n) {
    int gid = (blockIdx.x * blockDim.x + threadIdx.x) >> 4;   // node id
    int gl = threadIdx.x & 15;                                // lane in group
    if (gid >= n) return;
    int rs = rowstart[gid];
    int re = rowstart[gid + 1];
    float di = dinv[gid];
    int sub = gl >> 3;          // edge subslot 0/1
    int q = gl & 7;             // uint4 feature index
    int wbase = (threadIdx.x & 63) & 48;   // group's base lane within wave
    const uint4* yrow = (const uint4*)yin;
    float P0 = 0, P1 = 0, P2 = 0, P3 = 0, P4 = 0, P5 = 0, P6 = 0, P7 = 0;
    float sd = 0.0f;

    for (int base = rs; base < re; base += 16) {
        int idx = base + gl;
        bool ok = idx < re;
        int sj = ok ? (int)esrc[idx] : 0;
        float dj = ok ? dinv[sj] : 0.0f;
        sd += dj;
        int nn = re - base;
        if (nn > 16) nn = 16;
        for (int it = 0; it * 2 < nn; ++it) {
            int e = it * 2 + sub;
            int sl = wbase + e;
            int s0 = __shfl(sj, sl);
            float c0 = __shfl(dj, sl);
            uint4 v0 = yrow[(long)s0 * 8 + q];
            DECFMA(P0, P1, P2, P3, P4, P5, P6, P7, c0, v0)
        }
    }

    // fold the 2 subslots (bit 3 stays inside the 16-lane group)
    float t0 = P0 + __shfl_xor(P0, 8);
    float t1 = P1 + __shfl_xor(P1, 8);
    float t2 = P2 + __shfl_xor(P2, 8);
    float t3 = P3 + __shfl_xor(P3, 8);
    float t4 = P4 + __shfl_xor(P4, 8);
    float t5 = P5 + __shfl_xor(P5, 8);
    float t6 = P6 + __shfl_xor(P6, 8);
    float t7 = P7 + __shfl_xor(P7, 8);

    // self term
    uint4 sv = yrow[(long)gid * 8 + q];
    float dii = di * di;
    float o0 = fmaf(t0, di, BF_LO(sv.x) * dii);
    float o1 = fmaf(t1, di, BF_HI(sv.x) * dii);
    float o2 = fmaf(t2, di, BF_LO(sv.y) * dii);
    float o3 = fmaf(t3, di, BF_HI(sv.y) * dii);
    float o4 = fmaf(t4, di, BF_LO(sv.z) * dii);
    float o5 = fmaf(t5, di, BF_HI(sv.z) * dii);
    float o6 = fmaf(t6, di, BF_LO(sv.w) * dii);
    float o7 = fmaf(t7, di, BF_HI(sv.w) * dii);

    if (FINAL) {
        // sum dj over all 16 lanes of the group (bits 0..3)
        sd += __shfl_xor(sd, 1); sd += __shfl_xor(sd, 2);
        sd += __shfl_xor(sd, 4); sd += __shfl_xor(sd, 8);
        float si = di * (di + sd);
        int fo = q * 8;
        float4 bwa = *(const float4*)(bw + fo);
        float4 bwb = *(const float4*)(bw + fo + 4);
        float4 b2a = *(const float4*)(b2 + fo);
        float4 b2b = *(const float4*)(b2 + fo + 4);
        o0 = fmaf(si, bwa.x, o0) + b2a.x;
        o1 = fmaf(si, bwa.y, o1) + b2a.y;
        o2 = fmaf(si, bwa.z, o2) + b2a.z;
        o3 = fmaf(si, bwa.w, o3) + b2a.w;
        o4 = fmaf(si, bwb.x, o4) + b2b.x;
        o5 = fmaf(si, bwb.y, o5) + b2b.y;
        o6 = fmaf(si, bwb.z, o6) + b2b.z;
        o7 = fmaf(si, bwb.w, o7) + b2b.w;
        if (sub == 0) {
            float4 wa = {o0, o1, o2, o3};
            float4 wb = {o4, o5, o6, o7};
            *(float4*)(fout + (long)gid * 64 + q * 8) = wa;
            *(float4*)(fout + (long)gid * 64 + q * 8 + 4) = wb;
        }
    } else {
        if (sub == 0) {
            uint4 pk;
            pk.x = bf16pack(o0, o1);
            pk.y = bf16pack(o2, o3);
            pk.z = bf16pack(o4, o5);
            pk.w = bf16pack(o6, o7);
            *(uint4*)(zout + (long)gid * 64 + q * 8) = pk;
        }
    }
}

// ---------------------------------------------------------------------------
extern "C" void kernel_launch(void* const* d_in, const int* in_sizes, int n_in,
                              void* d_out, int out_size, void* d_ws, size_t ws_size,
                              hipStream_t stream) {
    const float* x  = (const float*)d_in[0];
    const int*   ei = (const int*)d_in[1];
    const float* W1 = (const float*)d_in[2];
    const float* b1 = (const float*)d_in[3];
    const float* W2 = (const float*)d_in[4];
    const float* b2 = (const float*)d_in[5];
    float* out = (float*)d_out;

    const int* src = ei;
    const int* dst = ei + N_EDGES;

    // workspace layout (bytes); z16 aliases ebuf (ebuf dead after bucket)
    char* ws = (char*)d_ws;
    float*  dinv     = (float*) (ws + 0);                // 204800
    int*    rowstart = (int*)   (ws + 204800);           // 204800 (n+1)
    int*    hist     = (int*)   (ws + 409600);           // 204800
    int*    scanned  = (int*)   (ws + 614400);           // 204800 (block-local)
    int*    bsum     = (int*)   (ws + 823296);           // 1024
    int*    boff     = (int*)   (ws + 824320);           // 1024
    float*  W12      = (float*) (ws + 825344);           // 24576
    float*  bw       = (float*) (ws + 849920);           // 512
    ushort* esrc     = (ushort*)(ws + 850432);           // 1600000 -> 2450432
    ushort* y16      = (ushort*)(ws + 2450432);          // 6400000 -> 8850432
    uint*   ebuf     = (uint*)  (ws + 8850432);          // 3200000 -> 12050432
    ushort* z16      = (ushort*)(ws + 8850432);          // 6400000 (aliases ebuf+)

    // Phase A: bucket edges by dst>>8 (full-line writes)
    histA_kernel<<<NBLKA, 256, 0, stream>>>(dst, hist);
    scan1_kernel<<<MSCAN / 256, 256, 0, stream>>>(hist, scanned, bsum, MSCAN);
    scan2_wfuse_kernel<<<26, 256, 0, stream>>>(bsum, boff, MSCAN / 256,
                                               W1, W2, b1, W12, bw);
    // scatter (blocks 0..199) || gemm y16 = x @ W12 (blocks 200..981)
    scatter_gemm_kernel<<<NBLKA + GEMMBLKS, 256, 0, stream>>>(
        src, dst, scanned, boff, ebuf, x, W12, y16, N_NODES);

    // Phase B: per-bucket rowstart + dinv + LDS-cursor scatter of esrc
    bucket_kernel<<<NBUCK, 256, 0, stream>>>(ebuf, scanned, boff, rowstart, dinv, esrc);

    // two aggregation passes: z16 = N y16 ; out = N z16 + si*bw + b2
    int aggBlocks = (N_NODES * 16 + 255) / 256;   // 16 lanes per node
    agg_kernel<false><<<aggBlocks, 256, 0, stream>>>(y16, rowstart, esrc, dinv,
                                                     bw, b2, z16, out, N_NODES);
    agg_kernel<true><<<aggBlocks, 256, 0, stream>>>(z16, rowstart, esrc, dinv,
                                                    bw, b2, z16, out, N_NODES);
}

// Round 15
// 86.115 us; speedup vs baseline: 5.9366x; 1.0003x over previous
//
#include <hip/hip_runtime.h>

#define N_NODES 50000
#define N_EDGES 800000
#define NBLKA 200                 // Phase-A blocks; 800000/200 = 4000 edges each
#define EPB (N_EDGES / NBLKA)     // 4000
#define NBUCK 196                 // ceil(50000/256) buckets of 256 nodes
#define MSCAN (256 * NBLKA)       // 51200 hist entries to scan
#define GEMMBLKS ((N_NODES + 63) / 64)   // 782

typedef unsigned int uint;
typedef unsigned short ushort;

// f32 -> bf16 RTNE pack of two values into one uint
__device__ __forceinline__ uint bf16pack(float a, float b) {
    uint ua = __float_as_uint(a); ua = (ua + 0x7FFFu + ((ua >> 16) & 1u)) >> 16;
    uint ub = __float_as_uint(b); ub = (ub + 0x7FFFu + ((ub >> 16) & 1u)) >> 16;
    return ua | (ub << 16);
}
#define BF_LO(U) __uint_as_float((U) << 16)
#define BF_HI(U) __uint_as_float((U) & 0xFFFF0000u)

// ---------------------------------------------------------------------------
// Phase A1: per-block 256-bin histogram of dst>>8, bin-major global layout.
// dst read as int4 (EPB=4000 divisible by 4*256? 4000/4=1000 int4s per block).
__global__ void histA_kernel(const int* __restrict__ dst, int* __restrict__ hist) {
    __shared__ int h[256];
    h[threadIdx.x] = 0;
    __syncthreads();
    const int4* d4 = (const int4*)(dst + blockIdx.x * EPB);
    for (int i = threadIdx.x; i < EPB / 4; i += 256) {
        int4 v = d4[i];
        atomicAdd(&h[v.x >> 8], 1);
        atomicAdd(&h[v.y >> 8], 1);
        atomicAdd(&h[v.z >> 8], 1);
        atomicAdd(&h[v.w >> 8], 1);
    }
    __syncthreads();
    hist[threadIdx.x * NBLKA + blockIdx.x] = h[threadIdx.x];
}

// ---------------------------------------------------------------------------
// scan1: block-local exclusive scan of hist -> scanned (local), bsum per block
__global__ void scan1_kernel(const int* __restrict__ in, int* __restrict__ out,
                             int* __restrict__ bsum, int n) {
    __shared__ int s[256];
    int i = blockIdx.x * 256 + threadIdx.x;
    int v = (i < n) ? in[i] : 0;
    s[threadIdx.x] = v;
    __syncthreads();
    for (int d = 1; d < 256; d <<= 1) {
        int t = (threadIdx.x >= d) ? s[threadIdx.x - d] : 0;
        __syncthreads();
        s[threadIdx.x] += t;
        __syncthreads();
    }
    if (i < n) out[i] = s[threadIdx.x] - v;
    if (threadIdx.x == 255) bsum[blockIdx.x] = s[255];
}

// scan2 (block 0) + wfuse (blocks 1..25) merged.
__global__ void scan2_wfuse_kernel(int* __restrict__ bsum, int* __restrict__ boff, int nb,
                                   const float* __restrict__ W1, const float* __restrict__ W2,
                                   const float* __restrict__ b1, float* __restrict__ W12,
                                   float* __restrict__ bw) {
    if (blockIdx.x == 0) {
        __shared__ int s[256];
        int t = threadIdx.x;
        int v = (t < nb) ? bsum[t] : 0;
        s[t] = v;
        __syncthreads();
        for (int d = 1; d < 256; d <<= 1) {
            int x = (t >= d) ? s[t - d] : 0;
            __syncthreads();
            s[t] += x;
            __syncthreads();
        }
        if (t < nb) boff[t] = s[t] - v;
        if (t == nb - 1) boff[nb] = s[t];
    } else {
        int idx = (blockIdx.x - 1) * 256 + threadIdx.x;
        if (idx < 96 * 64) {
            int k = idx >> 6, nn = idx & 63;
            float s = 0.0f;
#pragma unroll
            for (int j = 0; j < 96; ++j) s = fmaf(W1[k * 96 + j], W2[j * 64 + nn], s);
            W12[idx] = s;
        } else if (idx < 96 * 64 + 64) {
            int nn = idx - 96 * 64;
            float s = 0.0f;
#pragma unroll
            for (int j = 0; j < 96; ++j) s = fmaf(b1[j], W2[j * 64 + nn], s);
            bw[nn] = s;
        }
    }
}

// ---------------------------------------------------------------------------
// Merged Phase A2 scatter (blocks 0..NBLKA-1) + GEMM (blocks NBLKA..).
// gemm: W12 is 24KB, read-broadcast, L1-resident -> read DIRECTLY from global
// (dropping the sW LDS stage cut LDS 50->25.6KB: 3 -> 6 blocks/CU).
// ebuf entry packed: src(16b) | (dst&255)(8b) -- node ids < 65536.
#define FMA4(ACC, SCL, WV)                                                     \
    ACC.x = fmaf(SCL, WV.x, ACC.x);                                            \
    ACC.y = fmaf(SCL, WV.y, ACC.y);                                            \
    ACC.z = fmaf(SCL, WV.z, ACC.z);                                            \
    ACC.w = fmaf(SCL, WV.w, ACC.w);

__global__ __launch_bounds__(256)
void scatter_gemm_kernel(const int* __restrict__ src, const int* __restrict__ dst,
                         const int* __restrict__ scanned, const int* __restrict__ boff,
                         uint* __restrict__ ebuf,
                         const float* __restrict__ A, const float* __restrict__ W,
                         ushort* __restrict__ y16, int M) {
    __shared__ float smem[64 * 100];   // gemm: sA; scatter: off (aliased)
    int tid = threadIdx.x;

    if (blockIdx.x < NBLKA) {
        int* off = (int*)smem;
        int gi = tid * NBLKA + blockIdx.x;
        off[tid] = scanned[gi] + boff[gi >> 8];
        __syncthreads();
        int base = blockIdx.x * EPB;
        for (int i = base + tid; i < base + EPB; i += 256) {
            int s = src[i];
            int d = dst[i];
            int p = atomicAdd(&off[d >> 8], 1);
            ebuf[p] = (uint)s | ((uint)(d & 255) << 16);
        }
        return;
    }

    int bid = blockIdx.x - NBLKA;
    float* sA = smem;
    long row0 = (long)bid * 64;
    {   // stage A rows (coalesced float4; clamp for tail block)
        const float4* A4 = (const float4*)A;
        long base4 = row0 * 24;
        long lim = (long)M * 24 - 1;
        for (int f = tid; f < 64 * 24; f += 256) {
            long g = base4 + f;
            if (g > lim) g = lim;
            float4 v = A4[g];
            int r = f / 24, kc = f - r * 24;
            *(float4*)(sA + r * 100 + kc * 4) = v;
        }
    }
    __syncthreads();

    int tx = tid & 15;
    int ty = tid >> 4;
    float4 acc0 = {0, 0, 0, 0};
    float4 acc1 = {0, 0, 0, 0};
    float4 acc2 = {0, 0, 0, 0};
    float4 acc3 = {0, 0, 0, 0};
    const float* pa = sA + ty * 4 * 100;
    const float4* W4 = (const float4*)W;

#pragma unroll 1
    for (int k = 0; k < 96; k += 4) {
        float4 a0 = *(const float4*)(pa + 0 * 100 + k);
        float4 a1 = *(const float4*)(pa + 1 * 100 + k);
        float4 a2 = *(const float4*)(pa + 2 * 100 + k);
        float4 a3 = *(const float4*)(pa + 3 * 100 + k);
        float4 w0 = W4[(k + 0) * 16 + tx];
        float4 w1 = W4[(k + 1) * 16 + tx];
        float4 w2 = W4[(k + 2) * 16 + tx];
        float4 w3 = W4[(k + 3) * 16 + tx];
        FMA4(acc0, a0.x, w0) FMA4(acc0, a0.y, w1) FMA4(acc0, a0.z, w2) FMA4(acc0, a0.w, w3)
        FMA4(acc1, a1.x, w0) FMA4(acc1, a1.y, w1) FMA4(acc1, a1.z, w2) FMA4(acc1, a1.w, w3)
        FMA4(acc2, a2.x, w0) FMA4(acc2, a2.y, w1) FMA4(acc2, a2.z, w2) FMA4(acc2, a2.w, w3)
        FMA4(acc3, a3.x, w0) FMA4(acc3, a3.y, w1) FMA4(acc3, a3.z, w2) FMA4(acc3, a3.w, w3)
    }

    long r0 = row0 + ty * 4;
    uint2 p0 = {bf16pack(acc0.x, acc0.y), bf16pack(acc0.z, acc0.w)};
    uint2 p1 = {bf16pack(acc1.x, acc1.y), bf16pack(acc1.z, acc1.w)};
    uint2 p2 = {bf16pack(acc2.x, acc2.y), bf16pack(acc2.z, acc2.w)};
    uint2 p3 = {bf16pack(acc3.x, acc3.y), bf16pack(acc3.z, acc3.w)};
    if (r0 + 0 < M) *(uint2*)(y16 + (r0 + 0) * 64 + tx * 4) = p0;
    if (r0 + 1 < M) *(uint2*)(y16 + (r0 + 1) * 64 + tx * 4) = p1;
    if (r0 + 2 < M) *(uint2*)(y16 + (r0 + 2) * 64 + tx * 4) = p2;
    if (r0 + 3 < M) *(uint2*)(y16 + (r0 + 3) * 64 + tx * 4) = p3;
}

// ---------------------------------------------------------------------------
// Phase B: one block per 256-node bucket. LDS degree count -> rowstart + dinv,
// then LDS-cursor scatter of esrc (ushort src ids; no global atomics).
__global__ void bucket_kernel(const uint* __restrict__ ebuf, const int* __restrict__ scanned,
                              const int* __restrict__ boff, int* __restrict__ rowstart,
                              float* __restrict__ dinv, ushort* __restrict__ esrc) {
    __shared__ int cnt[256];
    __shared__ int cur[256];
    __shared__ int s[256];
    int k = blockIdx.x;
    int tid = threadIdx.x;
    int i0 = k * NBLKA, i1 = (k + 1) * NBLKA;
    int base = scanned[i0] + boff[i0 >> 8];
    int end  = (k == NBUCK - 1) ? N_EDGES : (scanned[i1] + boff[i1 >> 8]);
    cnt[tid] = 0;
    __syncthreads();
    for (int i = base + tid; i < end; i += 256)
        atomicAdd(&cnt[(ebuf[i] >> 16) & 255], 1);
    __syncthreads();
    int v = cnt[tid];
    s[tid] = v;
    __syncthreads();
    for (int d = 1; d < 256; d <<= 1) {
        int t = (tid >= d) ? s[tid - d] : 0;
        __syncthreads();
        s[tid] += t;
        __syncthreads();
    }
    int excl = s[tid] - v;
    int node = (k << 8) + tid;
    cur[tid] = base + excl;
    if (node < N_NODES) {
        rowstart[node] = base + excl;
        dinv[node] = rsqrtf((float)v + 1.0f);
    }
    if (k == 0 && tid == 0) rowstart[N_NODES] = N_EDGES;
    __syncthreads();
    for (int i = base + tid; i < end; i += 256) {
        uint e = ebuf[i];
        int p = atomicAdd(&cur[(e >> 16) & 255], 1);
        esrc[p] = (ushort)(e & 0xFFFFu);
    }
}

// ---------------------------------------------------------------------------
// Aggregation over bf16 rows, 16 LANES PER NODE (4 nodes/wave).
// Group = 16 lanes: 2 edge-subslots x 8 feature-lanes (uint4 = 8 bf16 each).
// Padded batch lanes carry dj=0 -> contribute 0; f32 accumulation.
#define DECFMA(A0, A1, A2, A3, A4, A5, A6, A7, C, V)                           \
    A0 = fmaf(BF_LO(V.x), C, A0); A1 = fmaf(BF_HI(V.x), C, A1);                \
    A2 = fmaf(BF_LO(V.y), C, A2); A3 = fmaf(BF_HI(V.y), C, A3);                \
    A4 = fmaf(BF_LO(V.z), C, A4); A5 = fmaf(BF_HI(V.z), C, A5);                \
    A6 = fmaf(BF_LO(V.w), C, A6); A7 = fmaf(BF_HI(V.w), C, A7);

template <bool FINAL>
__global__ __launch_bounds__(256)
void agg_kernel(const ushort* __restrict__ yin, const int* __restrict__ rowstart,
                const ushort* __restrict__ esrc, const float* __restrict__ dinv,
                const float* __restrict__ bw, const float* __restrict__ b2,
                ushort* __restrict__ zout, float* __restrict__ fout, int n) {
    int gid = (blockIdx.x * blockDim.x + threadIdx.x) >> 4;   // node id
    int gl = threadIdx.x & 15;                                // lane in group
    if (gid >= n) return;
    int rs = rowstart[gid];
    int re = rowstart[gid + 1];
    float di = dinv[gid];
    int sub = gl >> 3;          // edge subslot 0/1
    int q = gl & 7;             // uint4 feature index
    int wbase = (threadIdx.x & 63) & 48;   // group's base lane within wave
    const uint4* yrow = (const uint4*)yin;
    float P0 = 0, P1 = 0, P2 = 0, P3 = 0, P4 = 0, P5 = 0, P6 = 0, P7 = 0;
    float sd = 0.0f;

    for (int base = rs; base < re; base += 16) {
        int idx = base + gl;
        bool ok = idx < re;
        int sj = ok ? (int)esrc[idx] : 0;
        float dj = ok ? dinv[sj] : 0.0f;
        sd += dj;
        int nn = re - base;
        if (nn > 16) nn = 16;
        for (int it = 0; it * 2 < nn; ++it) {
            int e = it * 2 + sub;
            int sl = wbase + e;
            int s0 = __shfl(sj, sl);
            float c0 = __shfl(dj, sl);
            uint4 v0 = yrow[(long)s0 * 8 + q];
            DECFMA(P0, P1, P2, P3, P4, P5, P6, P7, c0, v0)
        }
    }

    // fold the 2 subslots (bit 3 stays inside the 16-lane group)
    float t0 = P0 + __shfl_xor(P0, 8);
    float t1 = P1 + __shfl_xor(P1, 8);
    float t2 = P2 + __shfl_xor(P2, 8);
    float t3 = P3 + __shfl_xor(P3, 8);
    float t4 = P4 + __shfl_xor(P4, 8);
    float t5 = P5 + __shfl_xor(P5, 8);
    float t6 = P6 + __shfl_xor(P6, 8);
    float t7 = P7 + __shfl_xor(P7, 8);

    // self term
    uint4 sv = yrow[(long)gid * 8 + q];
    float dii = di * di;
    float o0 = fmaf(t0, di, BF_LO(sv.x) * dii);
    float o1 = fmaf(t1, di, BF_HI(sv.x) * dii);
    float o2 = fmaf(t2, di, BF_LO(sv.y) * dii);
    float o3 = fmaf(t3, di, BF_HI(sv.y) * dii);
    float o4 = fmaf(t4, di, BF_LO(sv.z) * dii);
    float o5 = fmaf(t5, di, BF_HI(sv.z) * dii);
    float o6 = fmaf(t6, di, BF_LO(sv.w) * dii);
    float o7 = fmaf(t7, di, BF_HI(sv.w) * dii);

    if (FINAL) {
        // sum dj over all 16 lanes of the group (bits 0..3)
        sd += __shfl_xor(sd, 1); sd += __shfl_xor(sd, 2);
        sd += __shfl_xor(sd, 4); sd += __shfl_xor(sd, 8);
        float si = di * (di + sd);
        int fo = q * 8;
        float4 bwa = *(const float4*)(bw + fo);
        float4 bwb = *(const float4*)(bw + fo + 4);
        float4 b2a = *(const float4*)(b2 + fo);
        float4 b2b = *(const float4*)(b2 + fo + 4);
        o0 = fmaf(si, bwa.x, o0) + b2a.x;
        o1 = fmaf(si, bwa.y, o1) + b2a.y;
        o2 = fmaf(si, bwa.z, o2) + b2a.z;
        o3 = fmaf(si, bwa.w, o3) + b2a.w;
        o4 = fmaf(si, bwb.x, o4) + b2b.x;
        o5 = fmaf(si, bwb.y, o5) + b2b.y;
        o6 = fmaf(si, bwb.z, o6) + b2b.z;
        o7 = fmaf(si, bwb.w, o7) + b2b.w;
        if (sub == 0) {
            float4 wa = {o0, o1, o2, o3};
            float4 wb = {o4, o5, o6, o7};
            *(float4*)(fout + (long)gid * 64 + q * 8) = wa;
            *(float4*)(fout + (long)gid * 64 + q * 8 + 4) = wb;
        }
    } else {
        if (sub == 0) {
            uint4 pk;
            pk.x = bf16pack(o0, o1);
            pk.y = bf16pack(o2, o3);
            pk.z = bf16pack(o4, o5);
            pk.w = bf16pack(o6, o7);
            *(uint4*)(zout + (long)gid * 64 + q * 8) = pk;
        }
    }
}

// ---------------------------------------------------------------------------
extern "C" void kernel_launch(void* const* d_in, const int* in_sizes, int n_in,
                              void* d_out, int out_size, void* d_ws, size_t ws_size,
                              hipStream_t stream) {
    const float* x  = (const float*)d_in[0];
    const int*   ei = (const int*)d_in[1];
    const float* W1 = (const float*)d_in[2];
    const float* b1 = (const float*)d_in[3];
    const float* W2 = (const float*)d_in[4];
    const float* b2 = (const float*)d_in[5];
    float* out = (float*)d_out;

    const int* src = ei;
    const int* dst = ei + N_EDGES;

    // workspace layout (bytes); z16 aliases ebuf (ebuf dead after bucket)
    char* ws = (char*)d_ws;
    float*  dinv     = (float*) (ws + 0);                // 204800
    int*    rowstart = (int*)   (ws + 204800);           // 204800 (n+1)
    int*    hist     = (int*)   (ws + 409600);           // 204800
    int*    scanned  = (int*)   (ws + 614400);           // 204800 (block-local)
    int*    bsum     = (int*)   (ws + 823296);           // 1024
    int*    boff     = (int*)   (ws + 824320);           // 1024
    float*  W12      = (float*) (ws + 825344);           // 24576
    float*  bw       = (float*) (ws + 849920);           // 512
    ushort* esrc     = (ushort*)(ws + 850432);           // 1600000 -> 2450432
    ushort* y16      = (ushort*)(ws + 2450432);          // 6400000 -> 8850432
    uint*   ebuf     = (uint*)  (ws + 8850432);          // 3200000 -> 12050432
    ushort* z16      = (ushort*)(ws + 8850432);          // 6400000 (aliases ebuf+)

    // Phase A: bucket edges by dst>>8 (full-line writes)
    histA_kernel<<<NBLKA, 256, 0, stream>>>(dst, hist);
    scan1_kernel<<<MSCAN / 256, 256, 0, stream>>>(hist, scanned, bsum, MSCAN);
    scan2_wfuse_kernel<<<26, 256, 0, stream>>>(bsum, boff, MSCAN / 256,
                                               W1, W2, b1, W12, bw);
    // scatter (blocks 0..199) || gemm y16 = x @ W12 (blocks 200..981)
    scatter_gemm_kernel<<<NBLKA + GEMMBLKS, 256, 0, stream>>>(
        src, dst, scanned, boff, ebuf, x, W12, y16, N_NODES);

    // Phase B: per-bucket rowstart + dinv + LDS-cursor scatter of esrc
    bucket_kernel<<<NBUCK, 256, 0, stream>>>(ebuf, scanned, boff, rowstart, dinv, esrc);

    // two aggregation passes: z16 = N y16 ; out = N z16 + si*bw + b2
    int aggBlocks = (N_NODES * 16 + 255) / 256;   // 16 lanes per node
    agg_kernel<false><<<aggBlocks, 256, 0, stream>>>(y16, rowstart, esrc, dinv,
                                                     bw, b2, z16, out, N_NODES);
    agg_kernel<true><<<aggBlocks, 256, 0, stream>>>(z16, rowstart, esrc, dinv,
                                                    bw, b2, z16, out, N_NODES);
}